// Round 4
// baseline (252.121 us; speedup 1.0000x reference)
//
#include <hip/hip_runtime.h>
#include <hip/hip_bf16.h>

// STU forward. R17 = R16 + register read-ahead (counted-lgkm overlap) in the
//  8-phase K-loops + conv grid repack:
//  R16 counters: gemm_d 49.2us, MfmaUtil 30%, HBM 2.97/6.3 TB/s, conflicts 0.
//  Cycle budget per K-tile: MFMA 2483 cyc/CU + ds_read 2304 cyc/CU ~= the
//  5700-cyc tile => LDS reads and MFMA fully SERIALIZED (each phase reads
//  then immediately uses -> compiler lgkm drains before every MFMA; all
//  waves barrier-lockstepped so no cross-wave overlap either).
//  Fix: A-quadrant reg double-buffer (afA/afB): phase p issues ds_reads for
//  quadrant p+1 BEFORE its MFMA (which consumes the buffer read at p-1) ->
//  compiler emits counted lgkmcnt (first-use tracking), reads fly under
//  MFMA. Rings/gates/barriers/staging identical to the verified structure.
//  conv8 likewise + grid 536->512 (2 clean rounds: 256 heavy, then 256
//  light with the 24 phi jobs fused onto light blocks after a syncthreads).
// gemm_d (256x256 8-phase), gemm_r (paired 128x128), preps, ztaps as R16.
// NTAP=6, bf16 split-K partials, fused Phi chain, 6 launches, XOR swizzle.

using bf16 = __hip_bfloat16;
typedef __attribute__((ext_vector_type(8))) short bf16x8;
typedef __attribute__((ext_vector_type(4))) float f32x4;

#define B_   2
#define L_   1024
#define D_   512
#define K_   16
#define KT   17920      // 32*512 (conv channels) + 3*512 (M_u taps)
#define ROWS 2048       // B*L
#define NTAP 6          // AR taps s=1..6 (s=0 identity in fp32)
#define PBLD 3584       // PB row stride: 7 slots (s=0..6) * 512
#define SPLITD 14       // kc=1280; 224 main blocks + 32 phi = 256 = 1/CU
#define SPLITR 6        // one tap per split, K=512
#define ZBROWS 1032     // 8 guard rows + 1024 per batch
#define NKS 40          // Stage-D ksteps per block (kc/32)
#define NTD 20          // Stage-D K-tiles of 64 per block (NKS/2)
#define WZOFF 4194304   // zero W tile offset (elements): after uPT in region

// s_waitcnt imm: [3:0] vmcnt lo, [6:4] expcnt, [11:8] lgkmcnt, [15:14] vmcnt hi
#define WAIT_VM6 0x0F76   // vmcnt<=6 (3 stage-units = 6 loads/wave in flight)
#define WAIT_VM0 0x0F70

__device__ __forceinline__ void gll16(const void* g, void* l) {
    __builtin_amdgcn_global_load_lds(
        (const __attribute__((address_space(1))) unsigned int*)g,
        (__attribute__((address_space(3))) unsigned int*)l, 16, 0, 0);
}

// ---------------- prep: ALL prep work in one launch ----------------
__global__ void prep_all(const float* __restrict__ u, const float* __restrict__ fil,
                         const float* __restrict__ Mu, const float* __restrict__ My,
                         const float* __restrict__ Mp, const float* __restrict__ Mm,
                         bf16* __restrict__ U, bf16* __restrict__ BT,
                         bf16* __restrict__ PB, bf16* __restrict__ W,
                         bf16* __restrict__ Myb, bf16* __restrict__ BTT,
                         bf16* __restrict__ uPT) {
    __shared__ bf16 t[64][72];
    int bid = blockIdx.x, tid = threadIdx.x;
    auto pack4 = [](float4 v) {
        ushort4 o; bf16 h;
        h = __float2bfloat16(v.x); o.x = *(unsigned short*)&h;
        h = __float2bfloat16(v.y); o.y = *(unsigned short*)&h;
        h = __float2bfloat16(v.z); o.z = *(unsigned short*)&h;
        h = __float2bfloat16(v.w); o.w = *(unsigned short*)&h;
        return o;
    };
    if (bid < 3072) {                        // U taps
        int e4 = bid * 256 + tid;
        int r = e4 / 384, rem = e4 % 384;
        int tt = rem >> 7, f = (rem & 127) * 4;
        int b = r >> 10, l = r & 1023;
        float4 v = {0.f, 0.f, 0.f, 0.f};
        if (l >= tt) v = *(const float4*)&u[((size_t)b * L_ + l - tt) * D_ + f];
        *(ushort4*)&U[(size_t)r * KT + 16384 + tt * 512 + f] = pack4(v);
    } else if (bid < 3840) {                 // BT taps
        int e4 = (bid - 3072) * 256 + tid;
        int o = e4 / 384, tf4 = (e4 % 384) * 4;
        float4 v = *(const float4*)&Mu[(size_t)o * 1536 + tf4];
        *(ushort4*)&BT[(size_t)o * KT + 16384 + tf4] = pack4(v);
    } else if (bid < 4352) {                 // PB: P0=I, P1=M_y[:,0,:]
        int e4 = (bid - 3840) * 256 + tid;
        int n = e4 >> 8, c4 = (e4 & 255) * 4;
        float4 v;
        if (c4 < 512) {
            v.x = (n == c4) ? 1.f : 0.f;     v.y = (n == c4 + 1) ? 1.f : 0.f;
            v.z = (n == c4 + 2) ? 1.f : 0.f; v.w = (n == c4 + 3) ? 1.f : 0.f;
        } else v = *(const float4*)&My[(size_t)n * 1024 + (c4 - 512)];
        *(ushort4*)&PB[(size_t)n * PBLD + c4] = pack4(v);
    } else if (bid < 5120) {                 // Toeplitz W tiles (3 sets), pre-swizzled
        int tile = bid - 4352;
        int set = tile >> 8, rem = tile & 255;
        int k = rem >> 4, g = (rem >> 2) & 3, kb = rem & 3;
        for (int idx = tid; idx < 4096; idx += 256) {
            int i = idx >> 5, jp = idx & 31;
            int j = ((jp >> 3) ^ ((i >> 1) & 3)) * 8 + (jp & 7);
            int x = g * 128 + i - kb * 32 - j - (set == 2 ? 1 : 0);
            float v = 0.f;
            if (x >= 0) {
                int row = (set == 0) ? 2 * x : 2 * x + 1;
                v = fil[row * K_ + k];
            }
            W[(size_t)tile * 4096 + idx] = __float2bfloat16(v);
        }
    } else if (bid < 5632) {                 // Myb = bf16(My)
        int e4 = (bid - 5120) * 256 + tid;
        float4 v = *(const float4*)&My[(size_t)e4 * 4];
        *(ushort4*)&Myb[(size_t)e4 * 4] = pack4(v);
    } else if (bid < 7872) {                 // ---- transpose sections ----
        int tt = bid - 5632;                 // 2240 = 35 z * 64 (x,y)
        int zb = tt >> 6, rem = tt & 63;
        int bx = rem & 7, by = rem >> 3;
        int col = tid & 63, r0 = (tid >> 6) * 16;
        if (zb < 32) {                       // BT[o][c*512+d] = (Mp +/- Mm)[k][d][o]
            int dt = bx * 64, ot = by * 64, c = zb;
            int k = c & 15;
            const float* sp = Mp + (size_t)k * D_ * D_;
            const float* sm = Mm + (size_t)k * D_ * D_;
            float sg = (c < 16) ? 1.f : -1.f;
            for (int i = 0; i < 16; ++i) {
                size_t o_ = (size_t)(dt + r0 + i) * D_ + ot + col;
                t[r0 + i][col] = __float2bfloat16(sp[o_] + sg * sm[o_]);
            }
            __syncthreads();
            for (int i = 0; i < 16; ++i)
                BT[(size_t)(ot + r0 + i) * KT + c * D_ + dt + col] = t[col][r0 + i];
        } else if (zb < 34) {                // BTT[f][h*512+d] = M_y[d][1-h][f]
            int h = zb - 32;
            int dt = bx * 64, ft = by * 64;
            for (int i = 0; i < 16; ++i)
                t[r0 + i][col] = __float2bfloat16(My[(size_t)(dt + r0 + i) * 1024 + (1 - h) * 512 + ft + col]);
            __syncthreads();
            for (int i = 0; i < 16; ++i)
                BTT[(size_t)(ft + r0 + i) * 1024 + h * 512 + dt + col] = t[col][r0 + i];
        } else {                             // uPT[b][p][d][m'] = u[b][2m'+p][d]
            for (int it = 0; it < 4; ++it) {
                int b = it >> 1, p = it & 1;
                int mt = bx * 64, dt = by * 64;
                __syncthreads();
                for (int i = 0; i < 16; ++i)
                    t[r0 + i][col] = __float2bfloat16(u[((size_t)b * L_ + 2 * (mt + r0 + i) + p) * D_ + dt + col]);
                __syncthreads();
                for (int i = 0; i < 16; ++i)
                    uPT[((size_t)it * 512 + dt + r0 + i) * 512 + mt + col] = t[col][r0 + i];
            }
        }
    } else {                                 // zeroed W tile for conv8 A staging
        ushort4 z4 = {0, 0, 0, 0};
        for (int i = 0; i < 4; ++i)
            *(ushort4*)&W[(size_t)WZOFF + (size_t)(i * 256 + tid) * 4] = z4;
    }
}

// ---- shared body for small bf16-out GEMMs (4 waves; caller LDS) ----
__device__ __forceinline__ void phi_body(
    const bf16* A, int lda, const bf16* BT, int ldb,
    bf16* out, int ldo, int klen, const bf16* add, int lad,
    int row0, int col0, bf16* sA, bf16* sB)
{
    const int tid = threadIdx.x, lane = tid & 63, wave = tid >> 6;
    const int wm = (wave & 1) * 64, wn = (wave >> 1) * 64;
    const int ml = lane & 15, q = lane >> 4;
    const int srow = lane >> 2, scol = (((lane & 3) ^ ((srow >> 1) & 3))) * 8;
    const int swz = ((ml >> 1) & 3);
    f32x4 acc[4][4] = {};

    for (int k = 0; k < klen; k += 32) {
        __syncthreads();
        #pragma unroll
        for (int repi = 0; repi < 2; ++repi) {
            int a = wave + repi * 4;
            gll16(A  + (size_t)(row0 + a * 16 + srow) * lda + k + scol, &sA[a * 512]);
            gll16(BT + (size_t)(col0 + a * 16 + srow) * ldb + k + scol, &sB[a * 512]);
        }
        __syncthreads();
        bf16x8 af[4], bfr[4];
        #pragma unroll
        for (int i = 0; i < 4; ++i)
            af[i] = *(const bf16x8*)&sA[(wm + i * 16 + ml) * 32 + (q ^ swz) * 8];
        #pragma unroll
        for (int j = 0; j < 4; ++j)
            bfr[j] = *(const bf16x8*)&sB[(wn + j * 16 + ml) * 32 + (q ^ swz) * 8];
        #pragma unroll
        for (int i = 0; i < 4; ++i)
            #pragma unroll
            for (int j = 0; j < 4; ++j)
                acc[i][j] = __builtin_amdgcn_mfma_f32_16x16x32_bf16(af[i], bfr[j], acc[i][j], 0, 0, 0);
    }
    #pragma unroll
    for (int i = 0; i < 4; ++i)
        #pragma unroll
        for (int j = 0; j < 4; ++j)
            #pragma unroll
            for (int reg = 0; reg < 4; ++reg) {
                int r = row0 + wm + i * 16 + q * 4 + reg;
                int cc = col0 + wn + j * 16 + ml;
                float v = acc[i][j][reg];
                if (add) v += __bfloat162float(add[(size_t)r * lad + cc]);
                out[(size_t)r * ldo + cc] = __float2bfloat16(v);
            }
}

// ---- 8-wave variant: 128x256 output tile per block (for conv8 phi) ----
__device__ __forceinline__ void phi_body8(
    const bf16* A, int lda, const bf16* BT, int ldb,
    bf16* out, int ldo, int klen, const bf16* add, int lad,
    int row0, int col0, bf16* sA, bf16* sB)
{
    const int tid = threadIdx.x, lane = tid & 63, wave = tid >> 6;
    const int wm = (wave & 1) * 64, wn = (wave >> 1) * 64;   // 2M x 4N waves
    const int ml = lane & 15, q = lane >> 4;
    const int srow = lane >> 2, scol = (((lane & 3) ^ ((srow >> 1) & 3))) * 8;
    const int swz = ((ml >> 1) & 3);
    f32x4 acc[4][4] = {};

    for (int k = 0; k < klen; k += 32) {
        __syncthreads();
        gll16(A  + (size_t)(row0 + wave * 16 + srow) * lda + k + scol, &sA[wave * 512]);
        gll16(BT + (size_t)(col0 + (2 * wave) * 16 + srow) * ldb + k + scol, &sB[(2 * wave) * 512]);
        gll16(BT + (size_t)(col0 + (2 * wave + 1) * 16 + srow) * ldb + k + scol, &sB[(2 * wave + 1) * 512]);
        __syncthreads();
        bf16x8 af[4], bfr[4];
        #pragma unroll
        for (int i = 0; i < 4; ++i)
            af[i] = *(const bf16x8*)&sA[(wm + i * 16 + ml) * 32 + (q ^ swz) * 8];
        #pragma unroll
        for (int j = 0; j < 4; ++j)
            bfr[j] = *(const bf16x8*)&sB[(wn + j * 16 + ml) * 32 + (q ^ swz) * 8];
        #pragma unroll
        for (int i = 0; i < 4; ++i)
            #pragma unroll
            for (int j = 0; j < 4; ++j)
                acc[i][j] = __builtin_amdgcn_mfma_f32_16x16x32_bf16(af[i], bfr[j], acc[i][j], 0, 0, 0);
    }
    #pragma unroll
    for (int i = 0; i < 4; ++i)
        #pragma unroll
        for (int j = 0; j < 4; ++j)
            #pragma unroll
            for (int reg = 0; reg < 4; ++reg) {
                int r = row0 + wm + i * 16 + q * 4 + reg;
                int cc = col0 + wn + j * 16 + ml;
                float v = acc[i][j][reg];
                if (add) v += __bfloat162float(add[(size_t)r * lad + cc]);
                out[(size_t)r * ldo + cc] = __float2bfloat16(v);
            }
}

// sum 14 bf16 Stage-D partials -> z (fp32) + guard-padded bf16 copy zb
// bid<32: fused Phi doubling2 [P5|P6] = [P3|P4] x BTT (dispatched first)
// bid==32: zero the guard rows of zb
__global__ void k_ztaps(const bf16* __restrict__ partD, float* __restrict__ z,
                        bf16* __restrict__ zbuf, bf16* PB, const bf16* BTT) {
    __shared__ bf16 sA[4096];
    __shared__ bf16 sB[4096];
    int bid = blockIdx.x;
    if (bid < 32) {
        int row0 = (bid & 3) * 128, col0 = (bid >> 2) * 128;   // 4 x 8 tiles: 512x1024
        phi_body(PB + 3 * 512, PBLD, BTT, 1024, PB + 5 * 512, PBLD, 1024,
                 nullptr, 0, row0, col0, sA, sB);
        return;
    }
    if (bid == 32) {                         // zero 2x8 guard rows
        ushort4 z4 = {0, 0, 0, 0};
        for (int i = 0; i < 8; ++i) {
            int e4 = i * 256 + threadIdx.x;  // < 2048
            int b = e4 >> 10, rem = e4 & 1023;
            int g = rem >> 7, c4 = (rem & 127) * 4;
            *(ushort4*)&zbuf[(size_t)(b * ZBROWS + g) * 512 + c4] = z4;
        }
        return;
    }
    int t = (bid - 33) * 256 + threadIdx.x;  // ROWS*D_/4 threads exactly
    int r = t >> 7, f4 = (t & 127) * 4;
    const ushort4* p = (const ushort4*)partD;
    float4 s = {0.f, 0.f, 0.f, 0.f};
    #pragma unroll
    for (int c = 0; c < SPLITD; ++c) {
        ushort4 v = p[(size_t)c * (ROWS * D_ / 4) + t];
        s.x += __uint_as_float((unsigned)v.x << 16);
        s.y += __uint_as_float((unsigned)v.y << 16);
        s.z += __uint_as_float((unsigned)v.z << 16);
        s.w += __uint_as_float((unsigned)v.w << 16);
    }
    ((float4*)z)[t] = s;
    ushort4 zb4;
    { bf16 h;
      h = __float2bfloat16(s.x); zb4.x = *(unsigned short*)&h;
      h = __float2bfloat16(s.y); zb4.y = *(unsigned short*)&h;
      h = __float2bfloat16(s.z); zb4.z = *(unsigned short*)&h;
      h = __float2bfloat16(s.w); zb4.w = *(unsigned short*)&h; }
    int b = r >> 10, li = r & 1023;
    *(ushort4*)&zbuf[(size_t)(b * ZBROWS + 8 + li) * 512 + f4] = zb4;
}

// out = z + sum of SPLITR bf16 Stage-R partials
__global__ void reduce_out(const float* __restrict__ z, const bf16* __restrict__ partR,
                           float* __restrict__ out) {
    int t = blockIdx.x * 256 + threadIdx.x;
    if (t >= ROWS * D_ / 4) return;
    float4 s = ((const float4*)z)[t];
    const ushort4* p = (const ushort4*)partR;
    #pragma unroll
    for (int c = 0; c < SPLITR; ++c) {
        ushort4 v = p[(size_t)c * (ROWS * D_ / 4) + t];
        s.x += __uint_as_float((unsigned)v.x << 16);
        s.y += __uint_as_float((unsigned)v.y << 16);
        s.z += __uint_as_float((unsigned)v.z << 16);
        s.w += __uint_as_float((unsigned)v.w << 16);
    }
    ((float4*)out)[t] = s;
}

// ---- Stage C: 256x256 conv tiles, 512 threads, 8-phase + read-ahead --------
// grid 512 (2 clean rounds). id<256: heavy (mt2=1, K=512, NT=8).
// id>=256: light (mt2=0, K=256, NT=4); lid=id-256; lid<24 additionally runs
// one phi sub-tile (128x256) FIRST, then its conv block (syncthreads seam).
// zc=cid>>1, dt2=cid&1. A-SU = two pre-swizzled 128x32 W tiles; tile idx
// (rb - s/4)*4 + (s&3), below-diagonal -> zeroed tile (exact zeros).
__global__ __launch_bounds__(512, 2) void conv8(
    const bf16* __restrict__ W, const bf16* __restrict__ uPT,
    bf16* __restrict__ U,
    const bf16* PB, const bf16* BTT, const bf16* Myb)
{
    __shared__ bf16 sA[4][8192];
    __shared__ bf16 sB[4][8192];
    int id = blockIdx.x;
    const int tid = threadIdx.x, lane = tid & 63, wave = tid >> 6;
    if (id >= 256 && id < 280) {              // fused Phi chain on light blocks
        int sub = id - 256;
        int pz = sub >> 3, s8 = sub & 7;
        int row0 = (s8 & 3) * 128, col0 = (s8 >> 2) * 256;
        bf16* BTTw = (bf16*)BTT; bf16* PBw = (bf16*)PB;
        if (pz == 0)
            phi_body8(PB, PBLD, BTT, 1024, PBw + 2 * 512, PBLD, 1024,
                      nullptr, 0, row0, col0, &sA[0][0], &sB[0][0]);
        else if (pz == 1)
            phi_body8(BTT + 512, 1024, Myb + 512, 1024,
                      BTTw + (size_t)512 * 1024, 1024, 512,
                      nullptr, 0, row0, col0, &sA[0][0], &sB[0][0]);
        else
            phi_body8(BTT + 512, 1024, Myb, 1024,
                      BTTw + (size_t)512 * 1024 + 512, 1024, 512,
                      BTT, 1024, row0, col0, &sA[0][0], &sB[0][0]);
        __syncthreads();                      // LDS + vm drain before conv
    }
    const int cid = (id < 256) ? id : id - 256;
    const int mt2 = (id < 256) ? 1 : 0;
    const int zc = cid >> 1;
    const int dt2 = cid & 1;
    const int pc = zc & 3, b = (zc >> 2) & 1, k = zc >> 3;
    const int pb_ = pc & 1;
    const int p = (pc & 1) ^ (pc >> 1);
    const int set = (pc < 2) ? 0 : (pc == 2 ? 1 : 2);
    const int ch = (pc < 2) ? k : 16 + k;
    const int plane = b * 2 + pb_;
    const int nks = (mt2 + 1) * 8;            // 8 or 16 ksteps of 32
    const int NT = nks >> 1;                  // 4 or 8 K-tiles of 64

    const int wm = (wave >> 2) * 128;         // wave row half (2M)
    const int wn = (wave & 3) * 64;           // wave col quarter (4N)
    const int ml = lane & 15, q16 = lane >> 4;
    const int srow = lane >> 2, scol = (((lane & 3) ^ ((srow >> 1) & 3))) * 8;
    const int swz = ((ml >> 1) & 3);
    const int koff = (q16 ^ swz) * 8;

    const int a0 = 2 * wave, a1 = a0 + 1;     // 16 row-slots each for A and B
    const int rb = mt2 * 2 + (a0 >> 3);       // W 128-row block for this wave
    const bf16* wbase = W + ((size_t)(set * 16 + k) * 16) * 4096;
    const bf16* wzero = W + (size_t)WZOFF;
    const bf16* bB0 = uPT + ((size_t)plane * 512 + dt2 * 256 + a0 * 16 + srow) * 512 + scol;
    const bf16* bB1 = uPT + ((size_t)plane * 512 + dt2 * 256 + a1 * 16 + srow) * 512 + scol;

    auto stageA = [&](int s) {
        if (s >= nks) return;
        int s4 = s >> 2;
        const bf16* t0 = (rb >= s4)
            ? wbase + (size_t)((rb - s4) * 4 + (s & 3)) * 4096 : wzero;
        gll16(t0 + ((a0 & 7) * 512 + lane * 8), &sA[s & 3][a0 * 512]);
        gll16(t0 + ((a1 & 7) * 512 + lane * 8), &sA[s & 3][a1 * 512]);
    };
    auto stageB = [&](int s) {
        if (s >= nks) return;
        gll16(bB0 + s * 32, &sB[s & 3][a0 * 512]);
        gll16(bB1 + s * 32, &sB[s & 3][a1 * 512]);
    };

    f32x4 acc[8][4] = {};
    bf16x8 bfr[4][2], afA[2][2], afB[2][2];

    auto readB = [&](int u0, int u1) {
        #pragma unroll
        for (int fc = 0; fc < 4; ++fc) {
            bfr[fc][0] = *(const bf16x8*)&sB[u0][(wn + fc * 16 + ml) * 32 + koff];
            bfr[fc][1] = *(const bf16x8*)&sB[u1][(wn + fc * 16 + ml) * 32 + koff];
        }
    };
    auto readA = [&](bf16x8 (&af)[2][2], int u0, int u1, int q) {
        #pragma unroll
        for (int f2 = 0; f2 < 2; ++f2) {
            int R = wm + (2 * q + f2) * 16 + ml;
            af[f2][0] = *(const bf16x8*)&sA[u0][R * 32 + koff];
            af[f2][1] = *(const bf16x8*)&sA[u1][R * 32 + koff];
        }
    };
    auto mfma8 = [&](bf16x8 (&af)[2][2], int q) {
        __builtin_amdgcn_s_setprio(1);
        #pragma unroll
        for (int f2 = 0; f2 < 2; ++f2)
            #pragma unroll
            for (int fc = 0; fc < 4; ++fc) {
                acc[2 * q + f2][fc] = __builtin_amdgcn_mfma_f32_16x16x32_bf16(
                    af[f2][0], bfr[fc][0], acc[2 * q + f2][fc], 0, 0, 0);
                acc[2 * q + f2][fc] = __builtin_amdgcn_mfma_f32_16x16x32_bf16(
                    af[f2][1], bfr[fc][1], acc[2 * q + f2][fc], 0, 0, 0);
            }
        __builtin_amdgcn_s_setprio(0);
    };

    // prologue: tile0 + 3 SUs of lookahead in flight
    stageB(0); stageB(1); stageA(0); stageA(1);
    stageB(2); stageB(3); stageA(2);
    __builtin_amdgcn_s_waitcnt(WAIT_VM6);     // tile 0 landed
    __builtin_amdgcn_s_barrier();

    for (int t = 0; t < NT; ++t) {
        const int u0 = (2 * t) & 3, u1 = u0 + 1;
        // ph0: read B + Q0 (used now) + Q1 (ahead); stage; MFMA Q0
        readB(u0, u1);
        readA(afA, u0, u1, 0);
        readA(afB, u0, u1, 1);
        stageA(2 * t + 3);
        __builtin_amdgcn_s_barrier();
        mfma8(afA, 0);
        __builtin_amdgcn_s_barrier();
        // ph1: read Q2 (ahead); stage; MFMA Q1
        readA(afA, u0, u1, 2);
        stageB(2 * t + 4);
        __builtin_amdgcn_s_barrier();
        mfma8(afB, 1);
        __builtin_amdgcn_s_barrier();
        // ph2: read Q3 (ahead); stage; MFMA Q2
        readA(afB, u0, u1, 3);
        stageB(2 * t + 5);
        __builtin_amdgcn_s_barrier();
        mfma8(afA, 2);
        __builtin_amdgcn_s_barrier();
        // ph3: stage; MFMA Q3; gate
        stageA(2 * t + 4);
        __builtin_amdgcn_s_barrier();
        mfma8(afB, 3);
        if (t < NT - 2)       __builtin_amdgcn_s_waitcnt(WAIT_VM6);
        else if (t == NT - 2) __builtin_amdgcn_s_waitcnt(WAIT_VM0);
        __builtin_amdgcn_s_barrier();
    }

    #pragma unroll
    for (int i = 0; i < 8; ++i)
        #pragma unroll
        for (int j = 0; j < 4; ++j)
            #pragma unroll
            for (int reg = 0; reg < 4; ++reg) {
                int m = mt2 * 256 + wm + i * 16 + q16 * 4 + reg;
                int l = 2 * m + p;
                int d = dt2 * 256 + wn + j * 16 + ml;
                U[(size_t)(b * L_ + l) * KT + ch * 512 + d] = __float2bfloat16(acc[i][j][reg]);
            }
}

// ---- Stage D: 256x256 tiles, 512 threads, 8-phase + read-ahead -------------
// grid 256 (1-D, 1 block/CU). id<32: Phi doubling1 (waves 0-3 active).
// id>=32: id-=32; zz = id>>4 (14 splits); n_=id&15: row0=(n_>>1)*256,
// col0=(n_&1)*256. Waves 2Mx4N, wave tile 128x64, acc[8][4].
__global__ __launch_bounds__(512, 2) void gemm_d(
    const bf16* __restrict__ U, const bf16* __restrict__ BT,
    bf16* __restrict__ part, const bf16* PB, const bf16* BTT)
{
    __shared__ bf16 sA[4][8192];
    __shared__ bf16 sB[4][8192];
    int id = blockIdx.x;
    const int tid = threadIdx.x, lane = tid & 63, wave = tid >> 6;
    if (id < 32) {                            // doubling1: [P3|P4] = [P1|P2] x BTT
        if (wave >= 4) {                      // barrier-matched idle loop
            for (int i = 0; i < 64; ++i) __syncthreads();
            return;
        }
        int r0_ = (id & 3) * 128, c0_ = (id >> 2) * 128;   // 4x8 tiles: 512x1024
        phi_body(PB + 512, PBLD, BTT, 1024, (bf16*)PB + 3 * 512, PBLD, 1024,
                 nullptr, 0, r0_, c0_, &sA[0][0], &sB[0][0]);
        return;
    }
    id -= 32;                                 // 224 main blocks
    const int zz = id >> 4;                   // 14 splits
    const int n_ = id & 15;
    const int row0 = (n_ >> 1) * 256, col0 = (n_ & 1) * 256;
    const int k0 = zz * (KT / SPLITD);        // kc=1280 -> NKS=40 ksteps, NTD=20 tiles

    const int wm = (wave >> 2) * 128;         // wave row half (2M)
    const int wn = (wave & 3) * 64;           // wave col quarter (4N)
    const int ml = lane & 15, q16 = lane >> 4;
    const int srow = lane >> 2, scol = (((lane & 3) ^ ((srow >> 1) & 3))) * 8;
    const int swz = ((ml >> 1) & 3);
    const int koff = (q16 ^ swz) * 8;

    const int a0 = 2 * wave, a1 = 2 * wave + 1;   // 16 row-slots each for A and B
    const bf16* bA0 = U  + (size_t)(row0 + a0 * 16 + srow) * KT + k0 + scol;
    const bf16* bA1 = U  + (size_t)(row0 + a1 * 16 + srow) * KT + k0 + scol;
    const bf16* bB0 = BT + (size_t)(col0 + a0 * 16 + srow) * KT + k0 + scol;
    const bf16* bB1 = BT + (size_t)(col0 + a1 * 16 + srow) * KT + k0 + scol;
    auto stageA = [&](int s) {
        if (s >= NKS) return;
        gll16(bA0 + s * 32, &sA[s & 3][a0 * 512]);
        gll16(bA1 + s * 32, &sA[s & 3][a1 * 512]);
    };
    auto stageB = [&](int s) {
        if (s >= NKS) return;
        gll16(bB0 + s * 32, &sB[s & 3][a0 * 512]);
        gll16(bB1 + s * 32, &sB[s & 3][a1 * 512]);
    };

    f32x4 acc[8][4] = {};
    bf16x8 bfr[4][2], afA[2][2], afB[2][2];

    auto readB = [&](int u0, int u1) {
        #pragma unroll
        for (int fc = 0; fc < 4; ++fc) {
            bfr[fc][0] = *(const bf16x8*)&sB[u0][(wn + fc * 16 + ml) * 32 + koff];
            bfr[fc][1] = *(const bf16x8*)&sB[u1][(wn + fc * 16 + ml) * 32 + koff];
        }
    };
    auto readA = [&](bf16x8 (&af)[2][2], int u0, int u1, int q) {
        #pragma unroll
        for (int f2 = 0; f2 < 2; ++f2) {
            int R = wm + (2 * q + f2) * 16 + ml;
            af[f2][0] = *(const bf16x8*)&sA[u0][R * 32 + koff];
            af[f2][1] = *(const bf16x8*)&sA[u1][R * 32 + koff];
        }
    };
    auto mfma8 = [&](bf16x8 (&af)[2][2], int q) {
        __builtin_amdgcn_s_setprio(1);
        #pragma unroll
        for (int f2 = 0; f2 < 2; ++f2)
            #pragma unroll
            for (int fc = 0; fc < 4; ++fc) {
                acc[2 * q + f2][fc] = __builtin_amdgcn_mfma_f32_16x16x32_bf16(
                    af[f2][0], bfr[fc][0], acc[2 * q + f2][fc], 0, 0, 0);
                acc[2 * q + f2][fc] = __builtin_amdgcn_mfma_f32_16x16x32_bf16(
                    af[f2][1], bfr[fc][1], acc[2 * q + f2][fc], 0, 0, 0);
            }
        __builtin_amdgcn_s_setprio(0);
    };

    // prologue: tile0 + 3 SUs of lookahead in flight
    stageB(0); stageB(1); stageA(0); stageA(1);
    stageB(2); stageB(3); stageA(2);
    __builtin_amdgcn_s_waitcnt(WAIT_VM6);     // tile 0 landed (newest 3 SUs open)
    __builtin_amdgcn_s_barrier();

    for (int t = 0; t < NTD; ++t) {
        const int u0 = (2 * t) & 3, u1 = u0 + 1;
        // ph0: read B + Q0 (used now) + Q1 (ahead); stage; MFMA Q0
        readB(u0, u1);
        readA(afA, u0, u1, 0);
        readA(afB, u0, u1, 1);
        stageA(2 * t + 3);
        __builtin_amdgcn_s_barrier();
        mfma8(afA, 0);
        __builtin_amdgcn_s_barrier();
        // ph1: read Q2 (ahead); stage; MFMA Q1 (regs from ph0)
        readA(afA, u0, u1, 2);
        stageB(2 * t + 4);
        __builtin_amdgcn_s_barrier();
        mfma8(afB, 1);
        __builtin_amdgcn_s_barrier();
        // ph2: read Q3 (ahead); stage; MFMA Q2
        readA(afB, u0, u1, 3);
        stageB(2 * t + 5);
        __builtin_amdgcn_s_barrier();
        mfma8(afA, 2);
        __builtin_amdgcn_s_barrier();
        // ph3: stage; MFMA Q3; gate (next tile fully landed)
        stageA(2 * t + 4);
        __builtin_amdgcn_s_barrier();
        mfma8(afB, 3);
        if (t < NTD - 2)       __builtin_amdgcn_s_waitcnt(WAIT_VM6);
        else if (t == NTD - 2) __builtin_amdgcn_s_waitcnt(WAIT_VM0);
        __builtin_amdgcn_s_barrier();
    }

    bf16* o = part + (size_t)zz * ROWS * D_;
    #pragma unroll
    for (int i = 0; i < 8; ++i)
        #pragma unroll
        for (int j = 0; j < 4; ++j)
            #pragma unroll
            for (int reg = 0; reg < 4; ++reg) {
                int r = row0 + wm + i * 16 + q16 * 4 + reg;
                int cc = col0 + wn + j * 16 + ml;
                o[(size_t)r * D_ + cc] = __float2bfloat16(acc[i][j][reg]);
            }
}

// ---- paired-barrier 128x128 K-loop body (Stage R, n even) ------------------
__device__ __forceinline__ void mm128_pair(
    const bf16* Abase, int alda, const bf16* Bbase, int ldb, int n,
    bf16* o, int row0, int col0, bf16 (*sA)[4096], bf16 (*sB)[4096])
{
    const int tid = threadIdx.x, lane = tid & 63, wave = tid >> 6;
    const int wm = (wave & 1) * 64, wn = (wave >> 1) * 64;
    const int ml = lane & 15, q = lane >> 4;
    const int srow = lane >> 2, scol = (((lane & 3) ^ ((srow >> 1) & 3))) * 8;
    const int swz = ((ml >> 1) & 3);
    f32x4 acc[4][4] = {};

    const bf16* bA0 = Abase + (size_t)(wave * 16 + srow) * alda + scol;
    const bf16* bA1 = Abase + (size_t)((wave + 4) * 16 + srow) * alda + scol;
    const bf16* bB0 = Bbase + (size_t)(wave * 16 + srow) * ldb + scol;
    const bf16* bB1 = Bbase + (size_t)((wave + 4) * 16 + srow) * ldb + scol;
    auto stage = [&](int s) {
        int buf = s & 3;
        gll16(bA0 + s * 32, &sA[buf][wave * 512]);
        gll16(bA1 + s * 32, &sA[buf][(wave + 4) * 512]);
        gll16(bB0 + s * 32, &sB[buf][wave * 512]);
        gll16(bB1 + s * 32, &sB[buf][(wave + 4) * 512]);
    };
    auto compute = [&](int c) {
        bf16x8 af[4], bfr[4];
        #pragma unroll
        for (int i = 0; i < 4; ++i)
            af[i] = *(const bf16x8*)&sA[c][(wm + i * 16 + ml) * 32 + (q ^ swz) * 8];
        #pragma unroll
        for (int j = 0; j < 4; ++j)
            bfr[j] = *(const bf16x8*)&sB[c][(wn + j * 16 + ml) * 32 + (q ^ swz) * 8];
        #pragma unroll
        for (int i = 0; i < 4; ++i)
            #pragma unroll
            for (int j = 0; j < 4; ++j)
                acc[i][j] = __builtin_amdgcn_mfma_f32_16x16x32_bf16(af[i], bfr[j], acc[i][j], 0, 0, 0);
    };
    stage(0); stage(1);                       // pair 0
    const int npair = n >> 1;
    for (int p = 0; p < npair; ++p) {
        __builtin_amdgcn_s_waitcnt(WAIT_VM0); // pair p landed
        __builtin_amdgcn_s_barrier();
        if (2 * p + 2 < n) { stage(2 * p + 2); stage(2 * p + 3); } // pair p+1
        compute((2 * p) & 3);
        compute((2 * p + 1) & 3);
    }
    #pragma unroll
    for (int i = 0; i < 4; ++i)
        #pragma unroll
        for (int j = 0; j < 4; ++j)
            #pragma unroll
            for (int reg = 0; reg < 4; ++reg) {
                int r = row0 + wm + i * 16 + q * 4 + reg;
                int cc = col0 + wn + j * 16 + ml;
                o[(size_t)r * D_ + cc] = __float2bfloat16(acc[i][j][reg]);
            }
}

// Stage R: grid (16,4,6); A = guard-padded z taps in-place (tap s = zz+1).
__global__ __launch_bounds__(256, 2) void gemm_r(
    const bf16* __restrict__ zbuf, const bf16* __restrict__ BT,
    bf16* __restrict__ part)
{
    __shared__ bf16 sA[4][4096];
    __shared__ bf16 sB[4][4096];
    const int row0 = blockIdx.x * 128, col0 = blockIdx.y * 128;
    const int zz = blockIdx.z;
    const int s = 1 + zz;
    const int b = row0 >> 10, li0 = row0 & 1023;
    mm128_pair(zbuf + ((size_t)(b * ZBROWS + 8 + li0 - s)) * 512, 512,
               BT + (size_t)col0 * PBLD + (size_t)zz * 512, PBLD,
               16, part + (size_t)zz * ROWS * D_, row0, col0, sA, sB);
}

// ---------------- launch ----------------
extern "C" void kernel_launch(void* const* d_in, const int* in_sizes, int n_in,
                              void* d_out, int out_size, void* d_ws, size_t ws_size,
                              hipStream_t stream) {
    const float* u   = (const float*)d_in[0];
    const float* fil = (const float*)d_in[1];
    const float* Mu  = (const float*)d_in[2];
    const float* My  = (const float*)d_in[3];
    const float* Mp  = (const float*)d_in[4];
    const float* Mm  = (const float*)d_in[5];
    float* out = (float*)d_out;

    char* ws = (char*)d_ws;
    size_t off = 0;
    auto alloc = [&](size_t bytes) { void* p = ws + off; off = (off + bytes + 255) & ~(size_t)255; return p; };
    bf16*  U    = (bf16*) alloc((size_t)ROWS * KT * 2);        // 73.4 MB
    bf16*  BT   = (bf16*) alloc((size_t)512 * KT * 2);         // 18.4 MB
    bf16*  PB   = (bf16*) alloc((size_t)512 * PBLD * 2);       //  3.7 MB
    bf16*  BTT  = (bf16*) alloc((size_t)1024 * 1024 * 2);      //  2.1 MB
    bf16*  Myb  = (bf16*) alloc((size_t)512 * 1024 * 2);       //  1.0 MB
    float* z    = (float*)alloc((size_t)ROWS * D_ * 4);        //  4.2 MB
    bf16*  zb   = (bf16*) alloc((size_t)B_ * ZBROWS * 512 * 2);//  2.1 MB
    // overlapped region: {W + uPT + Wzero} dead after conv8; bf16 partD
    // written after; partD dead after k_ztaps; bf16 partR written after.
    char*  region = (char*)alloc((size_t)16 * ROWS * D_ * 2);  // 32 MB
    bf16*  W    = (bf16*)region;                               //  6.3 MB (768 tiles)
    bf16*  uPT  = (bf16*)(region + (size_t)768 * 4096 * 2);    //  2.1 MB
    // Wzero at W + WZOFF (elements) = region + 8.4 MB, 8 KB
    bf16*  partD = (bf16*)region;                              // 14 x 2 MB
    bf16*  partR = (bf16*)region;                              //  6 x 2 MB

    // all preps (1 launch; last block zeroes the conv8 zero-tile)
    prep_all<<<7873, 256, 0, stream>>>(u, fil, Mu, My, Mp, Mm,
                                       U, BT, PB, W, Myb, BTT, uPT);

    // Stage C: 8-phase 256x256 conv, 2 rounds (256 heavy; 256 light+24 phi)
    conv8<<<512, 512, 0, stream>>>(W, uPT, U, PB, BTT, Myb);

    // Stage D: 256x256 tiles, split-K 14, 8-phase + read-ahead + doubling1
    gemm_d<<<256, 512, 0, stream>>>(U, BT, partD, PB, BTT);

    // reduce partials -> z + guarded bf16 copy; Phi doubling2 fused (bid<32)
    k_ztaps<<<1057, 256, 0, stream>>>(partD, z, zb, PB, BTT);

    // Stage R: tap-partials, A = z taps in-place (6 splits = 1 tap each)
    gemm_r<<<dim3(16, 4, SPLITR), 256, 0, stream>>>(zb, PB + 512, partR);

    // out = z + sum partR
    reduce_out<<<(ROWS * D_ / 4 + 255) / 256, 256, 0, stream>>>(z, partR, out);
}

// Round 5
// 232.069 us; speedup vs baseline: 1.0864x; 1.0864x over previous
//
#include <hip/hip_runtime.h>
#include <hip/hip_bf16.h>

// STU forward. R18 = revert R17 regressions + pipeline the small-GEMM tails.
//  R17 post-mortem: register read-ahead NEUTRAL on gemm_d (reads already
//  overlap under the barrier wait + cross-wave overlap) and conv8 REGRESSED
//  46->64.5us (read-ahead + phi-before-conv serial tail on round-2 blocks).
//  => conv8/gemm_d reverted to the R16 forms (verified 231.7us total).
//  New this round: mmtile_pipe = the HW-verified conv_misc 3-buf vmcnt(4)
//  128x128 K-loop as a shared helper, replacing the 2-phase/full-drain
//  bodies at the two tail-pinning sites:
//   - k_ztaps bid<32 (Phi doubling2, K=1024: 32 drain-steps ~16us tail)
//   - gemm_r (was mm128_pair with vmcnt(0) per pair) + 3 blocks/CU.
//  Same per-32K-step MFMA order => bitwise-identical output.
// conv8 (536 grid: 24 phi_body8 + 256 heavy + 256 light, 8-phase),
// gemm_d (256x256 8-phase, vmcnt(6), setprio), preps, ztaps as R16.
// NTAP=6, bf16 split-K partials, fused Phi chain, 6 launches, XOR swizzle.

using bf16 = __hip_bfloat16;
typedef __attribute__((ext_vector_type(8))) short bf16x8;
typedef __attribute__((ext_vector_type(4))) float f32x4;

#define B_   2
#define L_   1024
#define D_   512
#define K_   16
#define KT   17920      // 32*512 (conv channels) + 3*512 (M_u taps)
#define ROWS 2048       // B*L
#define NTAP 6          // AR taps s=1..6 (s=0 identity in fp32)
#define PBLD 3584       // PB row stride: 7 slots (s=0..6) * 512
#define SPLITD 14       // kc=1280; 224 main blocks + 32 phi = 256 = 1/CU
#define SPLITR 6        // one tap per split, K=512
#define ZBROWS 1032     // 8 guard rows + 1024 per batch
#define NKS 40          // Stage-D ksteps per block (kc/32)
#define NTD 20          // Stage-D K-tiles of 64 per block (NKS/2)
#define WZOFF 4194304   // zero W tile offset (elements): after uPT in region

// s_waitcnt imm: [3:0] vmcnt lo, [6:4] expcnt, [11:8] lgkmcnt, [15:14] vmcnt hi
#define WAIT_VM6 0x0F76   // vmcnt<=6 (3 stage-units = 6 loads/wave in flight)
#define WAIT_VM4 0x0F74   // vmcnt<=4 (one stage = 4 loads/wave)
#define WAIT_VM0 0x0F70

__device__ __forceinline__ void gll16(const void* g, void* l) {
    __builtin_amdgcn_global_load_lds(
        (const __attribute__((address_space(1))) unsigned int*)g,
        (__attribute__((address_space(3))) unsigned int*)l, 16, 0, 0);
}

// ---------------- prep: ALL prep work in one launch ----------------
__global__ void prep_all(const float* __restrict__ u, const float* __restrict__ fil,
                         const float* __restrict__ Mu, const float* __restrict__ My,
                         const float* __restrict__ Mp, const float* __restrict__ Mm,
                         bf16* __restrict__ U, bf16* __restrict__ BT,
                         bf16* __restrict__ PB, bf16* __restrict__ W,
                         bf16* __restrict__ Myb, bf16* __restrict__ BTT,
                         bf16* __restrict__ uPT) {
    __shared__ bf16 t[64][72];
    int bid = blockIdx.x, tid = threadIdx.x;
    auto pack4 = [](float4 v) {
        ushort4 o; bf16 h;
        h = __float2bfloat16(v.x); o.x = *(unsigned short*)&h;
        h = __float2bfloat16(v.y); o.y = *(unsigned short*)&h;
        h = __float2bfloat16(v.z); o.z = *(unsigned short*)&h;
        h = __float2bfloat16(v.w); o.w = *(unsigned short*)&h;
        return o;
    };
    if (bid < 3072) {                        // U taps
        int e4 = bid * 256 + tid;
        int r = e4 / 384, rem = e4 % 384;
        int tt = rem >> 7, f = (rem & 127) * 4;
        int b = r >> 10, l = r & 1023;
        float4 v = {0.f, 0.f, 0.f, 0.f};
        if (l >= tt) v = *(const float4*)&u[((size_t)b * L_ + l - tt) * D_ + f];
        *(ushort4*)&U[(size_t)r * KT + 16384 + tt * 512 + f] = pack4(v);
    } else if (bid < 3840) {                 // BT taps
        int e4 = (bid - 3072) * 256 + tid;
        int o = e4 / 384, tf4 = (e4 % 384) * 4;
        float4 v = *(const float4*)&Mu[(size_t)o * 1536 + tf4];
        *(ushort4*)&BT[(size_t)o * KT + 16384 + tf4] = pack4(v);
    } else if (bid < 4352) {                 // PB: P0=I, P1=M_y[:,0,:]
        int e4 = (bid - 3840) * 256 + tid;
        int n = e4 >> 8, c4 = (e4 & 255) * 4;
        float4 v;
        if (c4 < 512) {
            v.x = (n == c4) ? 1.f : 0.f;     v.y = (n == c4 + 1) ? 1.f : 0.f;
            v.z = (n == c4 + 2) ? 1.f : 0.f; v.w = (n == c4 + 3) ? 1.f : 0.f;
        } else v = *(const float4*)&My[(size_t)n * 1024 + (c4 - 512)];
        *(ushort4*)&PB[(size_t)n * PBLD + c4] = pack4(v);
    } else if (bid < 5120) {                 // Toeplitz W tiles (3 sets), pre-swizzled
        int tile = bid - 4352;
        int set = tile >> 8, rem = tile & 255;
        int k = rem >> 4, g = (rem >> 2) & 3, kb = rem & 3;
        for (int idx = tid; idx < 4096; idx += 256) {
            int i = idx >> 5, jp = idx & 31;
            int j = ((jp >> 3) ^ ((i >> 1) & 3)) * 8 + (jp & 7);
            int x = g * 128 + i - kb * 32 - j - (set == 2 ? 1 : 0);
            float v = 0.f;
            if (x >= 0) {
                int row = (set == 0) ? 2 * x : 2 * x + 1;
                v = fil[row * K_ + k];
            }
            W[(size_t)tile * 4096 + idx] = __float2bfloat16(v);
        }
    } else if (bid < 5632) {                 // Myb = bf16(My)
        int e4 = (bid - 5120) * 256 + tid;
        float4 v = *(const float4*)&My[(size_t)e4 * 4];
        *(ushort4*)&Myb[(size_t)e4 * 4] = pack4(v);
    } else if (bid < 7872) {                 // ---- transpose sections ----
        int tt = bid - 5632;                 // 2240 = 35 z * 64 (x,y)
        int zb = tt >> 6, rem = tt & 63;
        int bx = rem & 7, by = rem >> 3;
        int col = tid & 63, r0 = (tid >> 6) * 16;
        if (zb < 32) {                       // BT[o][c*512+d] = (Mp +/- Mm)[k][d][o]
            int dt = bx * 64, ot = by * 64, c = zb;
            int k = c & 15;
            const float* sp = Mp + (size_t)k * D_ * D_;
            const float* sm = Mm + (size_t)k * D_ * D_;
            float sg = (c < 16) ? 1.f : -1.f;
            for (int i = 0; i < 16; ++i) {
                size_t o_ = (size_t)(dt + r0 + i) * D_ + ot + col;
                t[r0 + i][col] = __float2bfloat16(sp[o_] + sg * sm[o_]);
            }
            __syncthreads();
            for (int i = 0; i < 16; ++i)
                BT[(size_t)(ot + r0 + i) * KT + c * D_ + dt + col] = t[col][r0 + i];
        } else if (zb < 34) {                // BTT[f][h*512+d] = M_y[d][1-h][f]
            int h = zb - 32;
            int dt = bx * 64, ft = by * 64;
            for (int i = 0; i < 16; ++i)
                t[r0 + i][col] = __float2bfloat16(My[(size_t)(dt + r0 + i) * 1024 + (1 - h) * 512 + ft + col]);
            __syncthreads();
            for (int i = 0; i < 16; ++i)
                BTT[(size_t)(ft + r0 + i) * 1024 + h * 512 + dt + col] = t[col][r0 + i];
        } else {                             // uPT[b][p][d][m'] = u[b][2m'+p][d]
            for (int it = 0; it < 4; ++it) {
                int b = it >> 1, p = it & 1;
                int mt = bx * 64, dt = by * 64;
                __syncthreads();
                for (int i = 0; i < 16; ++i)
                    t[r0 + i][col] = __float2bfloat16(u[((size_t)b * L_ + 2 * (mt + r0 + i) + p) * D_ + dt + col]);
                __syncthreads();
                for (int i = 0; i < 16; ++i)
                    uPT[((size_t)it * 512 + dt + r0 + i) * 512 + mt + col] = t[col][r0 + i];
            }
        }
    } else {                                 // zeroed W tile for conv8 A staging
        ushort4 z4 = {0, 0, 0, 0};
        for (int i = 0; i < 4; ++i)
            *(ushort4*)&W[(size_t)WZOFF + (size_t)(i * 256 + tid) * 4] = z4;
    }
}

// ---- shared body for small bf16-out GEMMs (4 waves; caller LDS) ----
__device__ __forceinline__ void phi_body(
    const bf16* A, int lda, const bf16* BT, int ldb,
    bf16* out, int ldo, int klen, const bf16* add, int lad,
    int row0, int col0, bf16* sA, bf16* sB)
{
    const int tid = threadIdx.x, lane = tid & 63, wave = tid >> 6;
    const int wm = (wave & 1) * 64, wn = (wave >> 1) * 64;
    const int ml = lane & 15, q = lane >> 4;
    const int srow = lane >> 2, scol = (((lane & 3) ^ ((srow >> 1) & 3))) * 8;
    const int swz = ((ml >> 1) & 3);
    f32x4 acc[4][4] = {};

    for (int k = 0; k < klen; k += 32) {
        __syncthreads();
        #pragma unroll
        for (int repi = 0; repi < 2; ++repi) {
            int a = wave + repi * 4;
            gll16(A  + (size_t)(row0 + a * 16 + srow) * lda + k + scol, &sA[a * 512]);
            gll16(BT + (size_t)(col0 + a * 16 + srow) * ldb + k + scol, &sB[a * 512]);
        }
        __syncthreads();
        bf16x8 af[4], bfr[4];
        #pragma unroll
        for (int i = 0; i < 4; ++i)
            af[i] = *(const bf16x8*)&sA[(wm + i * 16 + ml) * 32 + (q ^ swz) * 8];
        #pragma unroll
        for (int j = 0; j < 4; ++j)
            bfr[j] = *(const bf16x8*)&sB[(wn + j * 16 + ml) * 32 + (q ^ swz) * 8];
        #pragma unroll
        for (int i = 0; i < 4; ++i)
            #pragma unroll
            for (int j = 0; j < 4; ++j)
                acc[i][j] = __builtin_amdgcn_mfma_f32_16x16x32_bf16(af[i], bfr[j], acc[i][j], 0, 0, 0);
    }
    #pragma unroll
    for (int i = 0; i < 4; ++i)
        #pragma unroll
        for (int j = 0; j < 4; ++j)
            #pragma unroll
            for (int reg = 0; reg < 4; ++reg) {
                int r = row0 + wm + i * 16 + q * 4 + reg;
                int cc = col0 + wn + j * 16 + ml;
                float v = acc[i][j][reg];
                if (add) v += __bfloat162float(add[(size_t)r * lad + cc]);
                out[(size_t)r * ldo + cc] = __float2bfloat16(v);
            }
}

// ---- 8-wave variant: 128x256 output tile per block (for conv8 phi) ----
__device__ __forceinline__ void phi_body8(
    const bf16* A, int lda, const bf16* BT, int ldb,
    bf16* out, int ldo, int klen, const bf16* add, int lad,
    int row0, int col0, bf16* sA, bf16* sB)
{
    const int tid = threadIdx.x, lane = tid & 63, wave = tid >> 6;
    const int wm = (wave & 1) * 64, wn = (wave >> 1) * 64;   // 2M x 4N waves
    const int ml = lane & 15, q = lane >> 4;
    const int srow = lane >> 2, scol = (((lane & 3) ^ ((srow >> 1) & 3))) * 8;
    const int swz = ((ml >> 1) & 3);
    f32x4 acc[4][4] = {};

    for (int k = 0; k < klen; k += 32) {
        __syncthreads();
        gll16(A  + (size_t)(row0 + wave * 16 + srow) * lda + k + scol, &sA[wave * 512]);
        gll16(BT + (size_t)(col0 + (2 * wave) * 16 + srow) * ldb + k + scol, &sB[(2 * wave) * 512]);
        gll16(BT + (size_t)(col0 + (2 * wave + 1) * 16 + srow) * ldb + k + scol, &sB[(2 * wave + 1) * 512]);
        __syncthreads();
        bf16x8 af[4], bfr[4];
        #pragma unroll
        for (int i = 0; i < 4; ++i)
            af[i] = *(const bf16x8*)&sA[(wm + i * 16 + ml) * 32 + (q ^ swz) * 8];
        #pragma unroll
        for (int j = 0; j < 4; ++j)
            bfr[j] = *(const bf16x8*)&sB[(wn + j * 16 + ml) * 32 + (q ^ swz) * 8];
        #pragma unroll
        for (int i = 0; i < 4; ++i)
            #pragma unroll
            for (int j = 0; j < 4; ++j)
                acc[i][j] = __builtin_amdgcn_mfma_f32_16x16x32_bf16(af[i], bfr[j], acc[i][j], 0, 0, 0);
    }
    #pragma unroll
    for (int i = 0; i < 4; ++i)
        #pragma unroll
        for (int j = 0; j < 4; ++j)
            #pragma unroll
            for (int reg = 0; reg < 4; ++reg) {
                int r = row0 + wm + i * 16 + q * 4 + reg;
                int cc = col0 + wn + j * 16 + ml;
                float v = acc[i][j][reg];
                if (add) v += __bfloat162float(add[(size_t)r * lad + cc]);
                out[(size_t)r * ldo + cc] = __float2bfloat16(v);
            }
}

// ---- 3-buf vmcnt(4) 128x128 K-loop (the verified conv_misc schedule) ------
// 4 waves. Abase/Bbase pre-offset to tile origin; epilogue uses row0/col0.
// Same per-32K-step MFMA order as phi_body/mm128_pair => identical numerics.
__device__ __forceinline__ void mmtile_pipe(
    const bf16* Abase, int lda, const bf16* Bbase, int ldb, int n,
    bf16* o, int ldo, int row0, int col0, bf16 (*sA)[4096], bf16 (*sB)[4096])
{
    const int tid = threadIdx.x, lane = tid & 63, wave = tid >> 6;
    const int wm = (wave & 1) * 64, wn = (wave >> 1) * 64;
    const int ml = lane & 15, q = lane >> 4;
    const int srow = lane >> 2, scol = (((lane & 3) ^ ((srow >> 1) & 3))) * 8;
    const int swz = ((ml >> 1) & 3);
    f32x4 acc[4][4] = {};

    const bf16* bA0 = Abase + (size_t)(wave * 16 + srow) * lda + scol;
    const bf16* bA1 = Abase + (size_t)((wave + 4) * 16 + srow) * lda + scol;
    const bf16* bB0 = Bbase + (size_t)(wave * 16 + srow) * ldb + scol;
    const bf16* bB1 = Bbase + (size_t)((wave + 4) * 16 + srow) * ldb + scol;
    auto stage = [&](int s, int buf) {
        gll16(bA0 + s * 32, &sA[buf][wave * 512]);
        gll16(bA1 + s * 32, &sA[buf][(wave + 4) * 512]);
        gll16(bB0 + s * 32, &sB[buf][wave * 512]);
        gll16(bB1 + s * 32, &sB[buf][(wave + 4) * 512]);
    };
    auto compute = [&](int c) {
        bf16x8 af[4], bfr[4];
        #pragma unroll
        for (int i = 0; i < 4; ++i)
            af[i] = *(const bf16x8*)&sA[c][(wm + i * 16 + ml) * 32 + (q ^ swz) * 8];
        #pragma unroll
        for (int j = 0; j < 4; ++j)
            bfr[j] = *(const bf16x8*)&sB[c][(wn + j * 16 + ml) * 32 + (q ^ swz) * 8];
        #pragma unroll
        for (int i = 0; i < 4; ++i)
            #pragma unroll
            for (int j = 0; j < 4; ++j)
                acc[i][j] = __builtin_amdgcn_mfma_f32_16x16x32_bf16(af[i], bfr[j], acc[i][j], 0, 0, 0);
    };
    stage(0, 0); stage(1, 1);
    int c = 0, nb = 2;
    for (int i = 0; i < n - 1; ++i) {
        __builtin_amdgcn_s_waitcnt(WAIT_VM4);
        __builtin_amdgcn_s_barrier();
        if (i + 2 < n) stage(i + 2, nb);
        compute(c);
        c = (c == 2) ? 0 : c + 1; nb = (nb == 2) ? 0 : nb + 1;
    }
    __builtin_amdgcn_s_waitcnt(WAIT_VM0);
    __builtin_amdgcn_s_barrier();
    compute(c);

    #pragma unroll
    for (int i = 0; i < 4; ++i)
        #pragma unroll
        for (int j = 0; j < 4; ++j)
            #pragma unroll
            for (int reg = 0; reg < 4; ++reg) {
                int r = row0 + wm + i * 16 + q * 4 + reg;
                int cc = col0 + wn + j * 16 + ml;
                o[(size_t)r * ldo + cc] = __float2bfloat16(acc[i][j][reg]);
            }
}

// sum 14 bf16 Stage-D partials -> z (fp32) + guard-padded bf16 copy zb
// bid<32: fused Phi doubling2 [P5|P6] = [P3|P4] x BTT (3-buf pipelined)
// bid==32: zero the guard rows of zb
__global__ void k_ztaps(const bf16* __restrict__ partD, float* __restrict__ z,
                        bf16* __restrict__ zbuf, bf16* PB, const bf16* BTT) {
    __shared__ bf16 sA[3][4096];
    __shared__ bf16 sB[3][4096];
    int bid = blockIdx.x;
    if (bid < 32) {
        int row0 = (bid & 3) * 128, col0 = (bid >> 2) * 128;   // 4 x 8 tiles: 512x1024
        mmtile_pipe(PB + 3 * 512 + (size_t)row0 * PBLD, PBLD,
                    BTT + (size_t)col0 * 1024, 1024, 32,
                    PB + 5 * 512, PBLD, row0, col0, sA, sB);
        return;
    }
    if (bid == 32) {                         // zero 2x8 guard rows
        ushort4 z4 = {0, 0, 0, 0};
        for (int i = 0; i < 8; ++i) {
            int e4 = i * 256 + threadIdx.x;  // < 2048
            int b = e4 >> 10, rem = e4 & 1023;
            int g = rem >> 7, c4 = (rem & 127) * 4;
            *(ushort4*)&zbuf[(size_t)(b * ZBROWS + g) * 512 + c4] = z4;
        }
        return;
    }
    int t = (bid - 33) * 256 + threadIdx.x;  // ROWS*D_/4 threads exactly
    int r = t >> 7, f4 = (t & 127) * 4;
    const ushort4* p = (const ushort4*)partD;
    float4 s = {0.f, 0.f, 0.f, 0.f};
    #pragma unroll
    for (int c = 0; c < SPLITD; ++c) {
        ushort4 v = p[(size_t)c * (ROWS * D_ / 4) + t];
        s.x += __uint_as_float((unsigned)v.x << 16);
        s.y += __uint_as_float((unsigned)v.y << 16);
        s.z += __uint_as_float((unsigned)v.z << 16);
        s.w += __uint_as_float((unsigned)v.w << 16);
    }
    ((float4*)z)[t] = s;
    ushort4 zb4;
    { bf16 h;
      h = __float2bfloat16(s.x); zb4.x = *(unsigned short*)&h;
      h = __float2bfloat16(s.y); zb4.y = *(unsigned short*)&h;
      h = __float2bfloat16(s.z); zb4.z = *(unsigned short*)&h;
      h = __float2bfloat16(s.w); zb4.w = *(unsigned short*)&h; }
    int b = r >> 10, li = r & 1023;
    *(ushort4*)&zbuf[(size_t)(b * ZBROWS + 8 + li) * 512 + f4] = zb4;
}

// out = z + sum of SPLITR bf16 Stage-R partials
__global__ void reduce_out(const float* __restrict__ z, const bf16* __restrict__ partR,
                           float* __restrict__ out) {
    int t = blockIdx.x * 256 + threadIdx.x;
    if (t >= ROWS * D_ / 4) return;
    float4 s = ((const float4*)z)[t];
    const ushort4* p = (const ushort4*)partR;
    #pragma unroll
    for (int c = 0; c < SPLITR; ++c) {
        ushort4 v = p[(size_t)c * (ROWS * D_ / 4) + t];
        s.x += __uint_as_float((unsigned)v.x << 16);
        s.y += __uint_as_float((unsigned)v.y << 16);
        s.z += __uint_as_float((unsigned)v.z << 16);
        s.w += __uint_as_float((unsigned)v.w << 16);
    }
    ((float4*)out)[t] = s;
}

// ---- Stage C: 256x256 conv tiles + phi, 512 threads, 8-phase schedule ------
// grid 536 (1-D, 1 block/CU). id<24: phi (8-wave, 128x256 tiles, 2-phase).
// id>=24: cid=id-24; mt2 = cid<256 (heavy K=512 first); zc=(cid&255)>>1,
// dt2=cid&1. A-SU stages from two pre-swizzled 128x32 W tiles; tile idx
// (rb - s/4)*4 + (s&3), below-diagonal -> zeroed tile (exact zeros).
__global__ __launch_bounds__(512, 2) void conv8(
    const bf16* __restrict__ W, const bf16* __restrict__ uPT,
    bf16* __restrict__ U,
    const bf16* PB, const bf16* BTT, const bf16* Myb)
{
    __shared__ bf16 sA[4][8192];
    __shared__ bf16 sB[4][8192];
    int id = blockIdx.x;
    const int tid = threadIdx.x, lane = tid & 63, wave = tid >> 6;
    if (id < 24) {                            // fused Phi chain, 8-wave tiles
        int pz = id >> 3, sub = id & 7;
        int row0 = (sub & 3) * 128, col0 = (sub >> 2) * 256;
        bf16* BTTw = (bf16*)BTT; bf16* PBw = (bf16*)PB;
        if (pz == 0)
            phi_body8(PB, PBLD, BTT, 1024, PBw + 2 * 512, PBLD, 1024,
                      nullptr, 0, row0, col0, &sA[0][0], &sB[0][0]);
        else if (pz == 1)
            phi_body8(BTT + 512, 1024, Myb + 512, 1024,
                      BTTw + (size_t)512 * 1024, 1024, 512,
                      nullptr, 0, row0, col0, &sA[0][0], &sB[0][0]);
        else
            phi_body8(BTT + 512, 1024, Myb, 1024,
                      BTTw + (size_t)512 * 1024 + 512, 1024, 512,
                      BTT, 1024, row0, col0, &sA[0][0], &sB[0][0]);
        return;
    }
    const int cid = id - 24;                  // 512 conv blocks, heavy first
    const int mt2 = (cid < 256) ? 1 : 0;
    const int zc = (cid & 255) >> 1;
    const int dt2 = cid & 1;
    const int pc = zc & 3, b = (zc >> 2) & 1, k = zc >> 3;
    const int pb_ = pc & 1;
    const int p = (pc & 1) ^ (pc >> 1);
    const int set = (pc < 2) ? 0 : (pc == 2 ? 1 : 2);
    const int ch = (pc < 2) ? k : 16 + k;
    const int plane = b * 2 + pb_;
    const int nks = (mt2 + 1) * 8;            // 8 or 16 ksteps of 32
    const int NT = nks >> 1;                  // 4 or 8 K-tiles of 64

    const int wm = (wave >> 2) * 128;         // wave row half (2M)
    const int wn = (wave & 3) * 64;           // wave col quarter (4N)
    const int ml = lane & 15, q16 = lane >> 4;
    const int srow = lane >> 2, scol = (((lane & 3) ^ ((srow >> 1) & 3))) * 8;
    const int swz = ((ml >> 1) & 3);
    const int koff = (q16 ^ swz) * 8;

    const int a0 = 2 * wave, a1 = a0 + 1;     // 16 row-slots each for A and B
    const int rb = mt2 * 2 + (a0 >> 3);       // W 128-row block for this wave
    const bf16* wbase = W + ((size_t)(set * 16 + k) * 16) * 4096;
    const bf16* wzero = W + (size_t)WZOFF;
    const bf16* bB0 = uPT + ((size_t)plane * 512 + dt2 * 256 + a0 * 16 + srow) * 512 + scol;
    const bf16* bB1 = uPT + ((size_t)plane * 512 + dt2 * 256 + a1 * 16 + srow) * 512 + scol;

    auto stageA = [&](int s) {
        if (s >= nks) return;
        int s4 = s >> 2;
        const bf16* t0 = (rb >= s4)
            ? wbase + (size_t)((rb - s4) * 4 + (s & 3)) * 4096 : wzero;
        gll16(t0 + ((a0 & 7) * 512 + lane * 8), &sA[s & 3][a0 * 512]);
        gll16(t0 + ((a1 & 7) * 512 + lane * 8), &sA[s & 3][a1 * 512]);
    };
    auto stageB = [&](int s) {
        if (s >= nks) return;
        gll16(bB0 + s * 32, &sB[s & 3][a0 * 512]);
        gll16(bB1 + s * 32, &sB[s & 3][a1 * 512]);
    };

    f32x4 acc[8][4] = {};

    // prologue: tile0 + 3 SUs of lookahead in flight
    stageB(0); stageB(1); stageA(0); stageA(1);
    stageB(2); stageB(3); stageA(2);
    __builtin_amdgcn_s_waitcnt(WAIT_VM6);     // tile 0 landed
    __builtin_amdgcn_s_barrier();

    for (int t = 0; t < NT; ++t) {
        const int u0 = (2 * t) & 3, u1 = u0 + 1;
        bf16x8 bfr[4][2];
        #pragma unroll
        for (int ph = 0; ph < 4; ++ph) {
            bf16x8 af[2][2];
            if (ph == 0) {                    // B whole K-tile -> regs (read once)
                #pragma unroll
                for (int fc = 0; fc < 4; ++fc) {
                    bfr[fc][0] = *(const bf16x8*)&sB[u0][(wn + fc * 16 + ml) * 32 + koff];
                    bfr[fc][1] = *(const bf16x8*)&sB[u1][(wn + fc * 16 + ml) * 32 + koff];
                }
            }
            #pragma unroll
            for (int f2 = 0; f2 < 2; ++f2) {  // A quadrant for this phase
                int R = wm + (2 * ph + f2) * 16 + ml;
                af[f2][0] = *(const bf16x8*)&sA[u0][R * 32 + koff];
                af[f2][1] = *(const bf16x8*)&sA[u1][R * 32 + koff];
            }
            if (ph == 0)      stageA(2 * t + 3);
            else if (ph == 1) stageB(2 * t + 4);
            else if (ph == 2) stageB(2 * t + 5);
            else              stageA(2 * t + 4);
            __builtin_amdgcn_s_barrier();
            __builtin_amdgcn_s_setprio(1);
            #pragma unroll
            for (int f2 = 0; f2 < 2; ++f2)
                #pragma unroll
                for (int fc = 0; fc < 4; ++fc) {
                    acc[2 * ph + f2][fc] = __builtin_amdgcn_mfma_f32_16x16x32_bf16(
                        af[f2][0], bfr[fc][0], acc[2 * ph + f2][fc], 0, 0, 0);
                    acc[2 * ph + f2][fc] = __builtin_amdgcn_mfma_f32_16x16x32_bf16(
                        af[f2][1], bfr[fc][1], acc[2 * ph + f2][fc], 0, 0, 0);
                }
            __builtin_amdgcn_s_setprio(0);
            if (ph == 3) {                    // gate: next tile fully landed
                if (t < NT - 2)       __builtin_amdgcn_s_waitcnt(WAIT_VM6);
                else if (t == NT - 2) __builtin_amdgcn_s_waitcnt(WAIT_VM0);
            }
            __builtin_amdgcn_s_barrier();
        }
    }

    #pragma unroll
    for (int i = 0; i < 8; ++i)
        #pragma unroll
        for (int j = 0; j < 4; ++j)
            #pragma unroll
            for (int reg = 0; reg < 4; ++reg) {
                int m = mt2 * 256 + wm + i * 16 + q16 * 4 + reg;
                int l = 2 * m + p;
                int d = dt2 * 256 + wn + j * 16 + ml;
                U[(size_t)(b * L_ + l) * KT + ch * 512 + d] = __float2bfloat16(acc[i][j][reg]);
            }
}

// ---- Stage D: 256x256 tiles, 512 threads, 8-phase schedule ------------------
// grid 256 (1-D, 1 block/CU). id<32: Phi doubling1 (waves 0-3 active).
// id>=32: id-=32; zz = id>>4 (14 splits); n_=id&15: row0=(n_>>1)*256,
// col0=(n_&1)*256. Waves 2Mx4N, wave tile 128x64, acc[8][4].
__global__ __launch_bounds__(512, 2) void gemm_d(
    const bf16* __restrict__ U, const bf16* __restrict__ BT,
    bf16* __restrict__ part, const bf16* PB, const bf16* BTT)
{
    __shared__ bf16 sA[4][8192];
    __shared__ bf16 sB[4][8192];
    int id = blockIdx.x;
    const int tid = threadIdx.x, lane = tid & 63, wave = tid >> 6;
    if (id < 32) {                            // doubling1: [P3|P4] = [P1|P2] x BTT
        if (wave >= 4) {                      // barrier-matched idle loop
            for (int i = 0; i < 64; ++i) __syncthreads();
            return;
        }
        int r0_ = (id & 3) * 128, c0_ = (id >> 2) * 128;   // 4x8 tiles: 512x1024
        phi_body(PB + 512, PBLD, BTT, 1024, (bf16*)PB + 3 * 512, PBLD, 1024,
                 nullptr, 0, r0_, c0_, &sA[0][0], &sB[0][0]);
        return;
    }
    id -= 32;                                 // 224 main blocks
    const int zz = id >> 4;                   // 14 splits
    const int n_ = id & 15;
    const int row0 = (n_ >> 1) * 256, col0 = (n_ & 1) * 256;
    const int k0 = zz * (KT / SPLITD);        // kc=1280 -> NKS=40 ksteps, NTD=20 tiles

    const int wm = (wave >> 2) * 128;         // wave row half (2M)
    const int wn = (wave & 3) * 64;           // wave col quarter (4N)
    const int ml = lane & 15, q16 = lane >> 4;
    const int srow = lane >> 2, scol = (((lane & 3) ^ ((srow >> 1) & 3))) * 8;
    const int swz = ((ml >> 1) & 3);
    const int koff = (q16 ^ swz) * 8;

    const int a0 = 2 * wave, a1 = 2 * wave + 1;   // 16 row-slots each for A and B
    const bf16* bA0 = U  + (size_t)(row0 + a0 * 16 + srow) * KT + k0 + scol;
    const bf16* bA1 = U  + (size_t)(row0 + a1 * 16 + srow) * KT + k0 + scol;
    const bf16* bB0 = BT + (size_t)(col0 + a0 * 16 + srow) * KT + k0 + scol;
    const bf16* bB1 = BT + (size_t)(col0 + a1 * 16 + srow) * KT + k0 + scol;
    auto stageA = [&](int s) {
        if (s >= NKS) return;
        gll16(bA0 + s * 32, &sA[s & 3][a0 * 512]);
        gll16(bA1 + s * 32, &sA[s & 3][a1 * 512]);
    };
    auto stageB = [&](int s) {
        if (s >= NKS) return;
        gll16(bB0 + s * 32, &sB[s & 3][a0 * 512]);
        gll16(bB1 + s * 32, &sB[s & 3][a1 * 512]);
    };

    f32x4 acc[8][4] = {};

    // prologue: tile0 + 3 SUs of lookahead in flight
    stageB(0); stageB(1); stageA(0); stageA(1);
    stageB(2); stageB(3); stageA(2);
    __builtin_amdgcn_s_waitcnt(WAIT_VM6);     // tile 0 landed (newest 3 SUs open)
    __builtin_amdgcn_s_barrier();

    for (int t = 0; t < NTD; ++t) {
        const int u0 = (2 * t) & 3, u1 = u0 + 1;
        bf16x8 bfr[4][2];
        #pragma unroll
        for (int ph = 0; ph < 4; ++ph) {
            bf16x8 af[2][2];
            if (ph == 0) {                    // B whole K-tile -> regs (read once)
                #pragma unroll
                for (int fc = 0; fc < 4; ++fc) {
                    bfr[fc][0] = *(const bf16x8*)&sB[u0][(wn + fc * 16 + ml) * 32 + koff];
                    bfr[fc][1] = *(const bf16x8*)&sB[u1][(wn + fc * 16 + ml) * 32 + koff];
                }
            }
            #pragma unroll
            for (int f2 = 0; f2 < 2; ++f2) {  // A quadrant for this phase
                int R = wm + (2 * ph + f2) * 16 + ml;
                af[f2][0] = *(const bf16x8*)&sA[u0][R * 32 + koff];
                af[f2][1] = *(const bf16x8*)&sA[u1][R * 32 + koff];
            }
            // stage one SU (WAR-safe stream: B slots free after ph0 reads,
            // A slots free after ph3 reads)
            if (ph == 0)      stageA(2 * t + 3);
            else if (ph == 1) stageB(2 * t + 4);
            else if (ph == 2) stageB(2 * t + 5);
            else              stageA(2 * t + 4);
            __builtin_amdgcn_s_barrier();
            __builtin_amdgcn_s_setprio(1);
            #pragma unroll
            for (int f2 = 0; f2 < 2; ++f2)
                #pragma unroll
                for (int fc = 0; fc < 4; ++fc) {
                    acc[2 * ph + f2][fc] = __builtin_amdgcn_mfma_f32_16x16x32_bf16(
                        af[f2][0], bfr[fc][0], acc[2 * ph + f2][fc], 0, 0, 0);
                    acc[2 * ph + f2][fc] = __builtin_amdgcn_mfma_f32_16x16x32_bf16(
                        af[f2][1], bfr[fc][1], acc[2 * ph + f2][fc], 0, 0, 0);
                }
            __builtin_amdgcn_s_setprio(0);
            if (ph == 3) {                    // gate: next tile fully landed
                if (t < NTD - 2)       __builtin_amdgcn_s_waitcnt(WAIT_VM6);
                else if (t == NTD - 2) __builtin_amdgcn_s_waitcnt(WAIT_VM0);
            }
            __builtin_amdgcn_s_barrier();
        }
    }

    bf16* o = part + (size_t)zz * ROWS * D_;
    #pragma unroll
    for (int i = 0; i < 8; ++i)
        #pragma unroll
        for (int j = 0; j < 4; ++j)
            #pragma unroll
            for (int reg = 0; reg < 4; ++reg) {
                int r = row0 + wm + i * 16 + q16 * 4 + reg;
                int cc = col0 + wn + j * 16 + ml;
                o[(size_t)r * D_ + cc] = __float2bfloat16(acc[i][j][reg]);
            }
}

// Stage R: grid (16,4,6); A = guard-padded z taps in-place (tap s = zz+1).
// 3-buf vmcnt(4) pipeline, 3 blocks/CU.
__global__ __launch_bounds__(256, 3) void gemm_r(
    const bf16* __restrict__ zbuf, const bf16* __restrict__ BT,
    bf16* __restrict__ part)
{
    __shared__ bf16 sA[3][4096];
    __shared__ bf16 sB[3][4096];
    const int row0 = blockIdx.x * 128, col0 = blockIdx.y * 128;
    const int zz = blockIdx.z;
    const int s = 1 + zz;
    const int b = row0 >> 10, li0 = row0 & 1023;
    mmtile_pipe(zbuf + ((size_t)(b * ZBROWS + 8 + li0 - s)) * 512, 512,
                BT + (size_t)col0 * PBLD + (size_t)zz * 512, PBLD,
                16, part + (size_t)zz * ROWS * D_, D_, row0, col0, sA, sB);
}

// ---------------- launch ----------------
extern "C" void kernel_launch(void* const* d_in, const int* in_sizes, int n_in,
                              void* d_out, int out_size, void* d_ws, size_t ws_size,
                              hipStream_t stream) {
    const float* u   = (const float*)d_in[0];
    const float* fil = (const float*)d_in[1];
    const float* Mu  = (const float*)d_in[2];
    const float* My  = (const float*)d_in[3];
    const float* Mp  = (const float*)d_in[4];
    const float* Mm  = (const float*)d_in[5];
    float* out = (float*)d_out;

    char* ws = (char*)d_ws;
    size_t off = 0;
    auto alloc = [&](size_t bytes) { void* p = ws + off; off = (off + bytes + 255) & ~(size_t)255; return p; };
    bf16*  U    = (bf16*) alloc((size_t)ROWS * KT * 2);        // 73.4 MB
    bf16*  BT   = (bf16*) alloc((size_t)512 * KT * 2);         // 18.4 MB
    bf16*  PB   = (bf16*) alloc((size_t)512 * PBLD * 2);       //  3.7 MB
    bf16*  BTT  = (bf16*) alloc((size_t)1024 * 1024 * 2);      //  2.1 MB
    bf16*  Myb  = (bf16*) alloc((size_t)512 * 1024 * 2);       //  1.0 MB
    float* z    = (float*)alloc((size_t)ROWS * D_ * 4);        //  4.2 MB
    bf16*  zb   = (bf16*) alloc((size_t)B_ * ZBROWS * 512 * 2);//  2.1 MB
    // overlapped region: {W + uPT + Wzero} dead after conv8; bf16 partD
    // written after; partD dead after k_ztaps; bf16 partR written after.
    char*  region = (char*)alloc((size_t)16 * ROWS * D_ * 2);  // 32 MB
    bf16*  W    = (bf16*)region;                               //  6.3 MB (768 tiles)
    bf16*  uPT  = (bf16*)(region + (size_t)768 * 4096 * 2);    //  2.1 MB
    // Wzero at W + WZOFF (elements) = region + 8.4 MB, 8 KB
    bf16*  partD = (bf16*)region;                              // 14 x 2 MB
    bf16*  partR = (bf16*)region;                              //  6 x 2 MB

    // all preps (1 launch; last block zeroes the conv8 zero-tile)
    prep_all<<<7873, 256, 0, stream>>>(u, fil, Mu, My, Mp, Mm,
                                       U, BT, PB, W, Myb, BTT, uPT);

    // Stage C: 8-phase 256x256 conv + 8-wave phi (24 phi + 512 conv blocks)
    conv8<<<536, 512, 0, stream>>>(W, uPT, U, PB, BTT, Myb);

    // Stage D: 256x256 tiles, split-K 14, 8-phase schedule + doubling1 (id<32)
    gemm_d<<<256, 512, 0, stream>>>(U, BT, partD, PB, BTT);

    // reduce partials -> z + guarded bf16 copy; Phi doubling2 (3-buf, bid<32)
    k_ztaps<<<1057, 256, 0, stream>>>(partD, z, zb, PB, BTT);

    // Stage R: tap-partials, A = z taps in-place (6 splits = 1 tap each)
    gemm_r<<<dim3(16, 4, SPLITR), 256, 0, stream>>>(zb, PB + 512, partR);

    // out = z + sum partR
    reduce_out<<<(ROWS * D_ / 4 + 255) / 256, 256, 0, stream>>>(z, partR, out);
}

// Round 6
// 229.727 us; speedup vs baseline: 1.0975x; 1.0102x over previous
//
#include <hip/hip_runtime.h>
#include <hip/hip_bf16.h>

// STU forward. R19 = R18 + T1 XCD-aware block swizzle on gemm_d and conv8.
//  R18 post-mortem: small-GEMM pipelining neutral (232.1 ~= 231.7); every
//  kernel <48.2us; gemm_d 48.2 top. New gemm_d theory: DELIVERY-bound —
//  ~300MB to LDS in 48.2us = 11.3 B/cyc/CU vs 20-23 achievable (m97/m201).
//  Cause: blocks sharing a BT column-panel (8x re-read, 0.65MB) round-robin
//  across all 8 XCDs -> re-reads served from L3/HBM not L2. Fix = T1:
//  gemm_d: bid%8 groups the 8 row-tiles of one (split,col) pair per XCD
//   (x=id&7, slot=id>>3, w=x*28+slot, g=w>>3, r=w&7; 4 phi + 28 main = 32
//   blocks/XCD, all resident). conv8: bid%8 = plane*2+dt2 so each XCD's 32
//   blocks share one 0.26MB uPT quarter + ~4MB W in its L2.
//  Pure index permutation — no schedule/numerics change (R17 lesson).
// conv8 (536: 24 phi + 256 heavy + 256 light, 8-phase), gemm_d (256x256
// 8-phase vmcnt(6) setprio), mmtile_pipe ztaps/gemm_r, preps as R18.
// NTAP=6, bf16 split-K partials, fused Phi chain, 6 launches, XOR swizzle.

using bf16 = __hip_bfloat16;
typedef __attribute__((ext_vector_type(8))) short bf16x8;
typedef __attribute__((ext_vector_type(4))) float f32x4;

#define B_   2
#define L_   1024
#define D_   512
#define K_   16
#define KT   17920      // 32*512 (conv channels) + 3*512 (M_u taps)
#define ROWS 2048       // B*L
#define NTAP 6          // AR taps s=1..6 (s=0 identity in fp32)
#define PBLD 3584       // PB row stride: 7 slots (s=0..6) * 512
#define SPLITD 14       // kc=1280; 224 main blocks + 32 phi = 256 = 1/CU
#define SPLITR 6        // one tap per split, K=512
#define ZBROWS 1032     // 8 guard rows + 1024 per batch
#define NKS 40          // Stage-D ksteps per block (kc/32)
#define NTD 20          // Stage-D K-tiles of 64 per block (NKS/2)
#define WZOFF 4194304   // zero W tile offset (elements): after uPT in region

// s_waitcnt imm: [3:0] vmcnt lo, [6:4] expcnt, [11:8] lgkmcnt, [15:14] vmcnt hi
#define WAIT_VM6 0x0F76   // vmcnt<=6 (3 stage-units = 6 loads/wave in flight)
#define WAIT_VM4 0x0F74   // vmcnt<=4 (one stage = 4 loads/wave)
#define WAIT_VM0 0x0F70

__device__ __forceinline__ void gll16(const void* g, void* l) {
    __builtin_amdgcn_global_load_lds(
        (const __attribute__((address_space(1))) unsigned int*)g,
        (__attribute__((address_space(3))) unsigned int*)l, 16, 0, 0);
}

// ---------------- prep: ALL prep work in one launch ----------------
__global__ void prep_all(const float* __restrict__ u, const float* __restrict__ fil,
                         const float* __restrict__ Mu, const float* __restrict__ My,
                         const float* __restrict__ Mp, const float* __restrict__ Mm,
                         bf16* __restrict__ U, bf16* __restrict__ BT,
                         bf16* __restrict__ PB, bf16* __restrict__ W,
                         bf16* __restrict__ Myb, bf16* __restrict__ BTT,
                         bf16* __restrict__ uPT) {
    __shared__ bf16 t[64][72];
    int bid = blockIdx.x, tid = threadIdx.x;
    auto pack4 = [](float4 v) {
        ushort4 o; bf16 h;
        h = __float2bfloat16(v.x); o.x = *(unsigned short*)&h;
        h = __float2bfloat16(v.y); o.y = *(unsigned short*)&h;
        h = __float2bfloat16(v.z); o.z = *(unsigned short*)&h;
        h = __float2bfloat16(v.w); o.w = *(unsigned short*)&h;
        return o;
    };
    if (bid < 3072) {                        // U taps
        int e4 = bid * 256 + tid;
        int r = e4 / 384, rem = e4 % 384;
        int tt = rem >> 7, f = (rem & 127) * 4;
        int b = r >> 10, l = r & 1023;
        float4 v = {0.f, 0.f, 0.f, 0.f};
        if (l >= tt) v = *(const float4*)&u[((size_t)b * L_ + l - tt) * D_ + f];
        *(ushort4*)&U[(size_t)r * KT + 16384 + tt * 512 + f] = pack4(v);
    } else if (bid < 3840) {                 // BT taps
        int e4 = (bid - 3072) * 256 + tid;
        int o = e4 / 384, tf4 = (e4 % 384) * 4;
        float4 v = *(const float4*)&Mu[(size_t)o * 1536 + tf4];
        *(ushort4*)&BT[(size_t)o * KT + 16384 + tf4] = pack4(v);
    } else if (bid < 4352) {                 // PB: P0=I, P1=M_y[:,0,:]
        int e4 = (bid - 3840) * 256 + tid;
        int n = e4 >> 8, c4 = (e4 & 255) * 4;
        float4 v;
        if (c4 < 512) {
            v.x = (n == c4) ? 1.f : 0.f;     v.y = (n == c4 + 1) ? 1.f : 0.f;
            v.z = (n == c4 + 2) ? 1.f : 0.f; v.w = (n == c4 + 3) ? 1.f : 0.f;
        } else v = *(const float4*)&My[(size_t)n * 1024 + (c4 - 512)];
        *(ushort4*)&PB[(size_t)n * PBLD + c4] = pack4(v);
    } else if (bid < 5120) {                 // Toeplitz W tiles (3 sets), pre-swizzled
        int tile = bid - 4352;
        int set = tile >> 8, rem = tile & 255;
        int k = rem >> 4, g = (rem >> 2) & 3, kb = rem & 3;
        for (int idx = tid; idx < 4096; idx += 256) {
            int i = idx >> 5, jp = idx & 31;
            int j = ((jp >> 3) ^ ((i >> 1) & 3)) * 8 + (jp & 7);
            int x = g * 128 + i - kb * 32 - j - (set == 2 ? 1 : 0);
            float v = 0.f;
            if (x >= 0) {
                int row = (set == 0) ? 2 * x : 2 * x + 1;
                v = fil[row * K_ + k];
            }
            W[(size_t)tile * 4096 + idx] = __float2bfloat16(v);
        }
    } else if (bid < 5632) {                 // Myb = bf16(My)
        int e4 = (bid - 5120) * 256 + tid;
        float4 v = *(const float4*)&My[(size_t)e4 * 4];
        *(ushort4*)&Myb[(size_t)e4 * 4] = pack4(v);
    } else if (bid < 7872) {                 // ---- transpose sections ----
        int tt = bid - 5632;                 // 2240 = 35 z * 64 (x,y)
        int zb = tt >> 6, rem = tt & 63;
        int bx = rem & 7, by = rem >> 3;
        int col = tid & 63, r0 = (tid >> 6) * 16;
        if (zb < 32) {                       // BT[o][c*512+d] = (Mp +/- Mm)[k][d][o]
            int dt = bx * 64, ot = by * 64, c = zb;
            int k = c & 15;
            const float* sp = Mp + (size_t)k * D_ * D_;
            const float* sm = Mm + (size_t)k * D_ * D_;
            float sg = (c < 16) ? 1.f : -1.f;
            for (int i = 0; i < 16; ++i) {
                size_t o_ = (size_t)(dt + r0 + i) * D_ + ot + col;
                t[r0 + i][col] = __float2bfloat16(sp[o_] + sg * sm[o_]);
            }
            __syncthreads();
            for (int i = 0; i < 16; ++i)
                BT[(size_t)(ot + r0 + i) * KT + c * D_ + dt + col] = t[col][r0 + i];
        } else if (zb < 34) {                // BTT[f][h*512+d] = M_y[d][1-h][f]
            int h = zb - 32;
            int dt = bx * 64, ft = by * 64;
            for (int i = 0; i < 16; ++i)
                t[r0 + i][col] = __float2bfloat16(My[(size_t)(dt + r0 + i) * 1024 + (1 - h) * 512 + ft + col]);
            __syncthreads();
            for (int i = 0; i < 16; ++i)
                BTT[(size_t)(ft + r0 + i) * 1024 + h * 512 + dt + col] = t[col][r0 + i];
        } else {                             // uPT[b][p][d][m'] = u[b][2m'+p][d]
            for (int it = 0; it < 4; ++it) {
                int b = it >> 1, p = it & 1;
                int mt = bx * 64, dt = by * 64;
                __syncthreads();
                for (int i = 0; i < 16; ++i)
                    t[r0 + i][col] = __float2bfloat16(u[((size_t)b * L_ + 2 * (mt + r0 + i) + p) * D_ + dt + col]);
                __syncthreads();
                for (int i = 0; i < 16; ++i)
                    uPT[((size_t)it * 512 + dt + r0 + i) * 512 + mt + col] = t[col][r0 + i];
            }
        }
    } else {                                 // zeroed W tile for conv8 A staging
        ushort4 z4 = {0, 0, 0, 0};
        for (int i = 0; i < 4; ++i)
            *(ushort4*)&W[(size_t)WZOFF + (size_t)(i * 256 + tid) * 4] = z4;
    }
}

// ---- shared body for small bf16-out GEMMs (4 waves; caller LDS) ----
__device__ __forceinline__ void phi_body(
    const bf16* A, int lda, const bf16* BT, int ldb,
    bf16* out, int ldo, int klen, const bf16* add, int lad,
    int row0, int col0, bf16* sA, bf16* sB)
{
    const int tid = threadIdx.x, lane = tid & 63, wave = tid >> 6;
    const int wm = (wave & 1) * 64, wn = (wave >> 1) * 64;
    const int ml = lane & 15, q = lane >> 4;
    const int srow = lane >> 2, scol = (((lane & 3) ^ ((srow >> 1) & 3))) * 8;
    const int swz = ((ml >> 1) & 3);
    f32x4 acc[4][4] = {};

    for (int k = 0; k < klen; k += 32) {
        __syncthreads();
        #pragma unroll
        for (int repi = 0; repi < 2; ++repi) {
            int a = wave + repi * 4;
            gll16(A  + (size_t)(row0 + a * 16 + srow) * lda + k + scol, &sA[a * 512]);
            gll16(BT + (size_t)(col0 + a * 16 + srow) * ldb + k + scol, &sB[a * 512]);
        }
        __syncthreads();
        bf16x8 af[4], bfr[4];
        #pragma unroll
        for (int i = 0; i < 4; ++i)
            af[i] = *(const bf16x8*)&sA[(wm + i * 16 + ml) * 32 + (q ^ swz) * 8];
        #pragma unroll
        for (int j = 0; j < 4; ++j)
            bfr[j] = *(const bf16x8*)&sB[(wn + j * 16 + ml) * 32 + (q ^ swz) * 8];
        #pragma unroll
        for (int i = 0; i < 4; ++i)
            #pragma unroll
            for (int j = 0; j < 4; ++j)
                acc[i][j] = __builtin_amdgcn_mfma_f32_16x16x32_bf16(af[i], bfr[j], acc[i][j], 0, 0, 0);
    }
    #pragma unroll
    for (int i = 0; i < 4; ++i)
        #pragma unroll
        for (int j = 0; j < 4; ++j)
            #pragma unroll
            for (int reg = 0; reg < 4; ++reg) {
                int r = row0 + wm + i * 16 + q * 4 + reg;
                int cc = col0 + wn + j * 16 + ml;
                float v = acc[i][j][reg];
                if (add) v += __bfloat162float(add[(size_t)r * lad + cc]);
                out[(size_t)r * ldo + cc] = __float2bfloat16(v);
            }
}

// ---- 8-wave variant: 128x256 output tile per block (for conv8 phi) ----
__device__ __forceinline__ void phi_body8(
    const bf16* A, int lda, const bf16* BT, int ldb,
    bf16* out, int ldo, int klen, const bf16* add, int lad,
    int row0, int col0, bf16* sA, bf16* sB)
{
    const int tid = threadIdx.x, lane = tid & 63, wave = tid >> 6;
    const int wm = (wave & 1) * 64, wn = (wave >> 1) * 64;   // 2M x 4N waves
    const int ml = lane & 15, q = lane >> 4;
    const int srow = lane >> 2, scol = (((lane & 3) ^ ((srow >> 1) & 3))) * 8;
    const int swz = ((ml >> 1) & 3);
    f32x4 acc[4][4] = {};

    for (int k = 0; k < klen; k += 32) {
        __syncthreads();
        gll16(A  + (size_t)(row0 + wave * 16 + srow) * lda + k + scol, &sA[wave * 512]);
        gll16(BT + (size_t)(col0 + (2 * wave) * 16 + srow) * ldb + k + scol, &sB[(2 * wave) * 512]);
        gll16(BT + (size_t)(col0 + (2 * wave + 1) * 16 + srow) * ldb + k + scol, &sB[(2 * wave + 1) * 512]);
        __syncthreads();
        bf16x8 af[4], bfr[4];
        #pragma unroll
        for (int i = 0; i < 4; ++i)
            af[i] = *(const bf16x8*)&sA[(wm + i * 16 + ml) * 32 + (q ^ swz) * 8];
        #pragma unroll
        for (int j = 0; j < 4; ++j)
            bfr[j] = *(const bf16x8*)&sB[(wn + j * 16 + ml) * 32 + (q ^ swz) * 8];
        #pragma unroll
        for (int i = 0; i < 4; ++i)
            #pragma unroll
            for (int j = 0; j < 4; ++j)
                acc[i][j] = __builtin_amdgcn_mfma_f32_16x16x32_bf16(af[i], bfr[j], acc[i][j], 0, 0, 0);
    }
    #pragma unroll
    for (int i = 0; i < 4; ++i)
        #pragma unroll
        for (int j = 0; j < 4; ++j)
            #pragma unroll
            for (int reg = 0; reg < 4; ++reg) {
                int r = row0 + wm + i * 16 + q * 4 + reg;
                int cc = col0 + wn + j * 16 + ml;
                float v = acc[i][j][reg];
                if (add) v += __bfloat162float(add[(size_t)r * lad + cc]);
                out[(size_t)r * ldo + cc] = __float2bfloat16(v);
            }
}

// ---- 3-buf vmcnt(4) 128x128 K-loop (the verified conv_misc schedule) ------
__device__ __forceinline__ void mmtile_pipe(
    const bf16* Abase, int lda, const bf16* Bbase, int ldb, int n,
    bf16* o, int ldo, int row0, int col0, bf16 (*sA)[4096], bf16 (*sB)[4096])
{
    const int tid = threadIdx.x, lane = tid & 63, wave = tid >> 6;
    const int wm = (wave & 1) * 64, wn = (wave >> 1) * 64;
    const int ml = lane & 15, q = lane >> 4;
    const int srow = lane >> 2, scol = (((lane & 3) ^ ((srow >> 1) & 3))) * 8;
    const int swz = ((ml >> 1) & 3);
    f32x4 acc[4][4] = {};

    const bf16* bA0 = Abase + (size_t)(wave * 16 + srow) * lda + scol;
    const bf16* bA1 = Abase + (size_t)((wave + 4) * 16 + srow) * lda + scol;
    const bf16* bB0 = Bbase + (size_t)(wave * 16 + srow) * ldb + scol;
    const bf16* bB1 = Bbase + (size_t)((wave + 4) * 16 + srow) * ldb + scol;
    auto stage = [&](int s, int buf) {
        gll16(bA0 + s * 32, &sA[buf][wave * 512]);
        gll16(bA1 + s * 32, &sA[buf][(wave + 4) * 512]);
        gll16(bB0 + s * 32, &sB[buf][wave * 512]);
        gll16(bB1 + s * 32, &sB[buf][(wave + 4) * 512]);
    };
    auto compute = [&](int c) {
        bf16x8 af[4], bfr[4];
        #pragma unroll
        for (int i = 0; i < 4; ++i)
            af[i] = *(const bf16x8*)&sA[c][(wm + i * 16 + ml) * 32 + (q ^ swz) * 8];
        #pragma unroll
        for (int j = 0; j < 4; ++j)
            bfr[j] = *(const bf16x8*)&sB[c][(wn + j * 16 + ml) * 32 + (q ^ swz) * 8];
        #pragma unroll
        for (int i = 0; i < 4; ++i)
            #pragma unroll
            for (int j = 0; j < 4; ++j)
                acc[i][j] = __builtin_amdgcn_mfma_f32_16x16x32_bf16(af[i], bfr[j], acc[i][j], 0, 0, 0);
    };
    stage(0, 0); stage(1, 1);
    int c = 0, nb = 2;
    for (int i = 0; i < n - 1; ++i) {
        __builtin_amdgcn_s_waitcnt(WAIT_VM4);
        __builtin_amdgcn_s_barrier();
        if (i + 2 < n) stage(i + 2, nb);
        compute(c);
        c = (c == 2) ? 0 : c + 1; nb = (nb == 2) ? 0 : nb + 1;
    }
    __builtin_amdgcn_s_waitcnt(WAIT_VM0);
    __builtin_amdgcn_s_barrier();
    compute(c);

    #pragma unroll
    for (int i = 0; i < 4; ++i)
        #pragma unroll
        for (int j = 0; j < 4; ++j)
            #pragma unroll
            for (int reg = 0; reg < 4; ++reg) {
                int r = row0 + wm + i * 16 + q * 4 + reg;
                int cc = col0 + wn + j * 16 + ml;
                o[(size_t)r * ldo + cc] = __float2bfloat16(acc[i][j][reg]);
            }
}

// sum 14 bf16 Stage-D partials -> z (fp32) + guard-padded bf16 copy zb
// bid<32: fused Phi doubling2 [P5|P6] = [P3|P4] x BTT (3-buf pipelined)
// bid==32: zero the guard rows of zb
__global__ void k_ztaps(const bf16* __restrict__ partD, float* __restrict__ z,
                        bf16* __restrict__ zbuf, bf16* PB, const bf16* BTT) {
    __shared__ bf16 sA[3][4096];
    __shared__ bf16 sB[3][4096];
    int bid = blockIdx.x;
    if (bid < 32) {
        int row0 = (bid & 3) * 128, col0 = (bid >> 2) * 128;   // 4 x 8 tiles: 512x1024
        mmtile_pipe(PB + 3 * 512 + (size_t)row0 * PBLD, PBLD,
                    BTT + (size_t)col0 * 1024, 1024, 32,
                    PB + 5 * 512, PBLD, row0, col0, sA, sB);
        return;
    }
    if (bid == 32) {                         // zero 2x8 guard rows
        ushort4 z4 = {0, 0, 0, 0};
        for (int i = 0; i < 8; ++i) {
            int e4 = i * 256 + threadIdx.x;  // < 2048
            int b = e4 >> 10, rem = e4 & 1023;
            int g = rem >> 7, c4 = (rem & 127) * 4;
            *(ushort4*)&zbuf[(size_t)(b * ZBROWS + g) * 512 + c4] = z4;
        }
        return;
    }
    int t = (bid - 33) * 256 + threadIdx.x;  // ROWS*D_/4 threads exactly
    int r = t >> 7, f4 = (t & 127) * 4;
    const ushort4* p = (const ushort4*)partD;
    float4 s = {0.f, 0.f, 0.f, 0.f};
    #pragma unroll
    for (int c = 0; c < SPLITD; ++c) {
        ushort4 v = p[(size_t)c * (ROWS * D_ / 4) + t];
        s.x += __uint_as_float((unsigned)v.x << 16);
        s.y += __uint_as_float((unsigned)v.y << 16);
        s.z += __uint_as_float((unsigned)v.z << 16);
        s.w += __uint_as_float((unsigned)v.w << 16);
    }
    ((float4*)z)[t] = s;
    ushort4 zb4;
    { bf16 h;
      h = __float2bfloat16(s.x); zb4.x = *(unsigned short*)&h;
      h = __float2bfloat16(s.y); zb4.y = *(unsigned short*)&h;
      h = __float2bfloat16(s.z); zb4.z = *(unsigned short*)&h;
      h = __float2bfloat16(s.w); zb4.w = *(unsigned short*)&h; }
    int b = r >> 10, li = r & 1023;
    *(ushort4*)&zbuf[(size_t)(b * ZBROWS + 8 + li) * 512 + f4] = zb4;
}

// out = z + sum of SPLITR bf16 Stage-R partials
__global__ void reduce_out(const float* __restrict__ z, const bf16* __restrict__ partR,
                           float* __restrict__ out) {
    int t = blockIdx.x * 256 + threadIdx.x;
    if (t >= ROWS * D_ / 4) return;
    float4 s = ((const float4*)z)[t];
    const ushort4* p = (const ushort4*)partR;
    #pragma unroll
    for (int c = 0; c < SPLITR; ++c) {
        ushort4 v = p[(size_t)c * (ROWS * D_ / 4) + t];
        s.x += __uint_as_float((unsigned)v.x << 16);
        s.y += __uint_as_float((unsigned)v.y << 16);
        s.z += __uint_as_float((unsigned)v.z << 16);
        s.w += __uint_as_float((unsigned)v.w << 16);
    }
    ((float4*)out)[t] = s;
}

// ---- Stage C: 256x256 conv tiles + phi, 512 threads, 8-phase schedule ------
// grid 536 (1-D, 1 block/CU). id<24: phi (8-wave, 128x256 tiles, 2-phase).
// id>=24: cid=id-24; mt2 = cid<256 (heavy K=512 first); m=cid&255.
// T1 decode: xcd8=m&7 -> (plane,dt2); slot=m>>3 -> (pc-bit, k). Each XCD's
// 32 same-class blocks share one uPT quarter (0.26MB) + W sets in its L2.
// A-SU = two pre-swizzled 128x32 W tiles; below-diagonal -> zeroed tile.
__global__ __launch_bounds__(512, 2) void conv8(
    const bf16* __restrict__ W, const bf16* __restrict__ uPT,
    bf16* __restrict__ U,
    const bf16* PB, const bf16* BTT, const bf16* Myb)
{
    __shared__ bf16 sA[4][8192];
    __shared__ bf16 sB[4][8192];
    int id = blockIdx.x;
    const int tid = threadIdx.x, lane = tid & 63, wave = tid >> 6;
    if (id < 24) {                            // fused Phi chain, 8-wave tiles
        int pz = id >> 3, sub = id & 7;
        int row0 = (sub & 3) * 128, col0 = (sub >> 2) * 256;
        bf16* BTTw = (bf16*)BTT; bf16* PBw = (bf16*)PB;
        if (pz == 0)
            phi_body8(PB, PBLD, BTT, 1024, PBw + 2 * 512, PBLD, 1024,
                      nullptr, 0, row0, col0, &sA[0][0], &sB[0][0]);
        else if (pz == 1)
            phi_body8(BTT + 512, 1024, Myb + 512, 1024,
                      BTTw + (size_t)512 * 1024, 1024, 512,
                      nullptr, 0, row0, col0, &sA[0][0], &sB[0][0]);
        else
            phi_body8(BTT + 512, 1024, Myb, 1024,
                      BTTw + (size_t)512 * 1024 + 512, 1024, 512,
                      BTT, 1024, row0, col0, &sA[0][0], &sB[0][0]);
        return;
    }
    const int cid = id - 24;                  // 512 conv blocks, heavy first
    const int mt2 = (cid < 256) ? 1 : 0;
    const int m = cid & 255;                  // (24 and 280 are both ==0 mod 8)
    const int xcd8 = m & 7, slot = m >> 3;    // T1: xcd8 = plane*2+dt2
    const int plane = xcd8 >> 1, dt2 = xcd8 & 1;
    const int pc = (plane & 1) | ((slot & 1) << 1);
    const int k = slot >> 1;
    const int b = plane >> 1;
    const int p = (pc & 1) ^ (pc >> 1);
    const int set = (pc < 2) ? 0 : (pc == 2 ? 1 : 2);
    const int ch = (pc < 2) ? k : 16 + k;
    const int nks = (mt2 + 1) * 8;            // 8 or 16 ksteps of 32
    const int NT = nks >> 1;                  // 4 or 8 K-tiles of 64

    const int wm = (wave >> 2) * 128;         // wave row half (2M)
    const int wn = (wave & 3) * 64;           // wave col quarter (4N)
    const int ml = lane & 15, q16 = lane >> 4;
    const int srow = lane >> 2, scol = (((lane & 3) ^ ((srow >> 1) & 3))) * 8;
    const int swz = ((ml >> 1) & 3);
    const int koff = (q16 ^ swz) * 8;

    const int a0 = 2 * wave, a1 = a0 + 1;     // 16 row-slots each for A and B
    const int rb = mt2 * 2 + (a0 >> 3);       // W 128-row block for this wave
    const bf16* wbase = W + ((size_t)(set * 16 + k) * 16) * 4096;
    const bf16* wzero = W + (size_t)WZOFF;
    const bf16* bB0 = uPT + ((size_t)plane * 512 + dt2 * 256 + a0 * 16 + srow) * 512 + scol;
    const bf16* bB1 = uPT + ((size_t)plane * 512 + dt2 * 256 + a1 * 16 + srow) * 512 + scol;

    auto stageA = [&](int s) {
        if (s >= nks) return;
        int s4 = s >> 2;
        const bf16* t0 = (rb >= s4)
            ? wbase + (size_t)((rb - s4) * 4 + (s & 3)) * 4096 : wzero;
        gll16(t0 + ((a0 & 7) * 512 + lane * 8), &sA[s & 3][a0 * 512]);
        gll16(t0 + ((a1 & 7) * 512 + lane * 8), &sA[s & 3][a1 * 512]);
    };
    auto stageB = [&](int s) {
        if (s >= nks) return;
        gll16(bB0 + s * 32, &sB[s & 3][a0 * 512]);
        gll16(bB1 + s * 32, &sB[s & 3][a1 * 512]);
    };

    f32x4 acc[8][4] = {};

    // prologue: tile0 + 3 SUs of lookahead in flight
    stageB(0); stageB(1); stageA(0); stageA(1);
    stageB(2); stageB(3); stageA(2);
    __builtin_amdgcn_s_waitcnt(WAIT_VM6);     // tile 0 landed
    __builtin_amdgcn_s_barrier();

    for (int t = 0; t < NT; ++t) {
        const int u0 = (2 * t) & 3, u1 = u0 + 1;
        bf16x8 bfr[4][2];
        #pragma unroll
        for (int ph = 0; ph < 4; ++ph) {
            bf16x8 af[2][2];
            if (ph == 0) {                    // B whole K-tile -> regs (read once)
                #pragma unroll
                for (int fc = 0; fc < 4; ++fc) {
                    bfr[fc][0] = *(const bf16x8*)&sB[u0][(wn + fc * 16 + ml) * 32 + koff];
                    bfr[fc][1] = *(const bf16x8*)&sB[u1][(wn + fc * 16 + ml) * 32 + koff];
                }
            }
            #pragma unroll
            for (int f2 = 0; f2 < 2; ++f2) {  // A quadrant for this phase
                int R = wm + (2 * ph + f2) * 16 + ml;
                af[f2][0] = *(const bf16x8*)&sA[u0][R * 32 + koff];
                af[f2][1] = *(const bf16x8*)&sA[u1][R * 32 + koff];
            }
            if (ph == 0)      stageA(2 * t + 3);
            else if (ph == 1) stageB(2 * t + 4);
            else if (ph == 2) stageB(2 * t + 5);
            else              stageA(2 * t + 4);
            __builtin_amdgcn_s_barrier();
            __builtin_amdgcn_s_setprio(1);
            #pragma unroll
            for (int f2 = 0; f2 < 2; ++f2)
                #pragma unroll
                for (int fc = 0; fc < 4; ++fc) {
                    acc[2 * ph + f2][fc] = __builtin_amdgcn_mfma_f32_16x16x32_bf16(
                        af[f2][0], bfr[fc][0], acc[2 * ph + f2][fc], 0, 0, 0);
                    acc[2 * ph + f2][fc] = __builtin_amdgcn_mfma_f32_16x16x32_bf16(
                        af[f2][1], bfr[fc][1], acc[2 * ph + f2][fc], 0, 0, 0);
                }
            __builtin_amdgcn_s_setprio(0);
            if (ph == 3) {                    // gate: next tile fully landed
                if (t < NT - 2)       __builtin_amdgcn_s_waitcnt(WAIT_VM6);
                else if (t == NT - 2) __builtin_amdgcn_s_waitcnt(WAIT_VM0);
            }
            __builtin_amdgcn_s_barrier();
        }
    }

    #pragma unroll
    for (int i = 0; i < 8; ++i)
        #pragma unroll
        for (int j = 0; j < 4; ++j)
            #pragma unroll
            for (int reg = 0; reg < 4; ++reg) {
                int mm = mt2 * 256 + wm + i * 16 + q16 * 4 + reg;
                int l = 2 * mm + p;
                int d = dt2 * 256 + wn + j * 16 + ml;
                U[(size_t)(b * L_ + l) * KT + ch * 512 + d] = __float2bfloat16(acc[i][j][reg]);
            }
}

// ---- Stage D: 256x256 tiles, 512 threads, 8-phase schedule ------------------
// grid 256 (1-D, 1 block/CU). id<32: Phi doubling1 (waves 0-3 active).
// id>=32: id-=32; T1 decode: x=id&7 (XCD), slot=id>>3, w=x*28+slot,
// g=w>>3 (= split*2+col), r=w&7 (row tile). The 8 row-tiles sharing one
// (split,col) BT panel (0.65MB, 8x re-read) land on ONE XCD -> L2-resident.
// 4 phi + 28 main = 32 blocks/XCD, all resident. Waves 2Mx4N, acc[8][4].
__global__ __launch_bounds__(512, 2) void gemm_d(
    const bf16* __restrict__ U, const bf16* __restrict__ BT,
    bf16* __restrict__ part, const bf16* PB, const bf16* BTT)
{
    __shared__ bf16 sA[4][8192];
    __shared__ bf16 sB[4][8192];
    int id = blockIdx.x;
    const int tid = threadIdx.x, lane = tid & 63, wave = tid >> 6;
    if (id < 32) {                            // doubling1: [P3|P4] = [P1|P2] x BTT
        if (wave >= 4) {                      // barrier-matched idle loop
            for (int i = 0; i < 64; ++i) __syncthreads();
            return;
        }
        int r0_ = (id & 3) * 128, c0_ = (id >> 2) * 128;   // 4x8 tiles: 512x1024
        phi_body(PB + 512, PBLD, BTT, 1024, (bf16*)PB + 3 * 512, PBLD, 1024,
                 nullptr, 0, r0_, c0_, &sA[0][0], &sB[0][0]);
        return;
    }
    id -= 32;                                 // 224 main blocks
    const int xsw = id & 7, slot = id >> 3;   // T1 swizzle (bijective 8x28)
    const int w_ = xsw * 28 + slot;
    const int g = w_ >> 3, rtile = w_ & 7;
    const int zz = g >> 1;                    // 14 splits
    const int row0 = rtile * 256, col0 = (g & 1) * 256;
    const int k0 = zz * (KT / SPLITD);        // kc=1280 -> NKS=40 ksteps, NTD=20 tiles

    const int wm = (wave >> 2) * 128;         // wave row half (2M)
    const int wn = (wave & 3) * 64;           // wave col quarter (4N)
    const int ml = lane & 15, q16 = lane >> 4;
    const int srow = lane >> 2, scol = (((lane & 3) ^ ((srow >> 1) & 3))) * 8;
    const int swz = ((ml >> 1) & 3);
    const int koff = (q16 ^ swz) * 8;

    const int a0 = 2 * wave, a1 = 2 * wave + 1;   // 16 row-slots each for A and B
    const bf16* bA0 = U  + (size_t)(row0 + a0 * 16 + srow) * KT + k0 + scol;
    const bf16* bA1 = U  + (size_t)(row0 + a1 * 16 + srow) * KT + k0 + scol;
    const bf16* bB0 = BT + (size_t)(col0 + a0 * 16 + srow) * KT + k0 + scol;
    const bf16* bB1 = BT + (size_t)(col0 + a1 * 16 + srow) * KT + k0 + scol;
    auto stageA = [&](int s) {
        if (s >= NKS) return;
        gll16(bA0 + s * 32, &sA[s & 3][a0 * 512]);
        gll16(bA1 + s * 32, &sA[s & 3][a1 * 512]);
    };
    auto stageB = [&](int s) {
        if (s >= NKS) return;
        gll16(bB0 + s * 32, &sB[s & 3][a0 * 512]);
        gll16(bB1 + s * 32, &sB[s & 3][a1 * 512]);
    };

    f32x4 acc[8][4] = {};

    // prologue: tile0 + 3 SUs of lookahead in flight
    stageB(0); stageB(1); stageA(0); stageA(1);
    stageB(2); stageB(3); stageA(2);
    __builtin_amdgcn_s_waitcnt(WAIT_VM6);     // tile 0 landed (newest 3 SUs open)
    __builtin_amdgcn_s_barrier();

    for (int t = 0; t < NTD; ++t) {
        const int u0 = (2 * t) & 3, u1 = u0 + 1;
        bf16x8 bfr[4][2];
        #pragma unroll
        for (int ph = 0; ph < 4; ++ph) {
            bf16x8 af[2][2];
            if (ph == 0) {                    // B whole K-tile -> regs (read once)
                #pragma unroll
                for (int fc = 0; fc < 4; ++fc) {
                    bfr[fc][0] = *(const bf16x8*)&sB[u0][(wn + fc * 16 + ml) * 32 + koff];
                    bfr[fc][1] = *(const bf16x8*)&sB[u1][(wn + fc * 16 + ml) * 32 + koff];
                }
            }
            #pragma unroll
            for (int f2 = 0; f2 < 2; ++f2) {  // A quadrant for this phase
                int R = wm + (2 * ph + f2) * 16 + ml;
                af[f2][0] = *(const bf16x8*)&sA[u0][R * 32 + koff];
                af[f2][1] = *(const bf16x8*)&sA[u1][R * 32 + koff];
            }
            // stage one SU (WAR-safe stream: B slots free after ph0 reads,
            // A slots free after ph3 reads)
            if (ph == 0)      stageA(2 * t + 3);
            else if (ph == 1) stageB(2 * t + 4);
            else if (ph == 2) stageB(2 * t + 5);
            else              stageA(2 * t + 4);
            __builtin_amdgcn_s_barrier();
            __builtin_amdgcn_s_setprio(1);
            #pragma unroll
            for (int f2 = 0; f2 < 2; ++f2)
                #pragma unroll
                for (int fc = 0; fc < 4; ++fc) {
                    acc[2 * ph + f2][fc] = __builtin_amdgcn_mfma_f32_16x16x32_bf16(
                        af[f2][0], bfr[fc][0], acc[2 * ph + f2][fc], 0, 0, 0);
                    acc[2 * ph + f2][fc] = __builtin_amdgcn_mfma_f32_16x16x32_bf16(
                        af[f2][1], bfr[fc][1], acc[2 * ph + f2][fc], 0, 0, 0);
                }
            __builtin_amdgcn_s_setprio(0);
            if (ph == 3) {                    // gate: next tile fully landed
                if (t < NTD - 2)       __builtin_amdgcn_s_waitcnt(WAIT_VM6);
                else if (t == NTD - 2) __builtin_amdgcn_s_waitcnt(WAIT_VM0);
            }
            __builtin_amdgcn_s_barrier();
        }
    }

    bf16* o = part + (size_t)zz * ROWS * D_;
    #pragma unroll
    for (int i = 0; i < 8; ++i)
        #pragma unroll
        for (int j = 0; j < 4; ++j)
            #pragma unroll
            for (int reg = 0; reg < 4; ++reg) {
                int r = row0 + wm + i * 16 + q16 * 4 + reg;
                int cc = col0 + wn + j * 16 + ml;
                o[(size_t)r * D_ + cc] = __float2bfloat16(acc[i][j][reg]);
            }
}

// Stage R: grid (16,4,6); A = guard-padded z taps in-place (tap s = zz+1).
// 3-buf vmcnt(4) pipeline, 3 blocks/CU.
__global__ __launch_bounds__(256, 3) void gemm_r(
    const bf16* __restrict__ zbuf, const bf16* __restrict__ BT,
    bf16* __restrict__ part)
{
    __shared__ bf16 sA[3][4096];
    __shared__ bf16 sB[3][4096];
    const int row0 = blockIdx.x * 128, col0 = blockIdx.y * 128;
    const int zz = blockIdx.z;
    const int s = 1 + zz;
    const int b = row0 >> 10, li0 = row0 & 1023;
    mmtile_pipe(zbuf + ((size_t)(b * ZBROWS + 8 + li0 - s)) * 512, 512,
                BT + (size_t)col0 * PBLD + (size_t)zz * 512, PBLD,
                16, part + (size_t)zz * ROWS * D_, D_, row0, col0, sA, sB);
}

// ---------------- launch ----------------
extern "C" void kernel_launch(void* const* d_in, const int* in_sizes, int n_in,
                              void* d_out, int out_size, void* d_ws, size_t ws_size,
                              hipStream_t stream) {
    const float* u   = (const float*)d_in[0];
    const float* fil = (const float*)d_in[1];
    const float* Mu  = (const float*)d_in[2];
    const float* My  = (const float*)d_in[3];
    const float* Mp  = (const float*)d_in[4];
    const float* Mm  = (const float*)d_in[5];
    float* out = (float*)d_out;

    char* ws = (char*)d_ws;
    size_t off = 0;
    auto alloc = [&](size_t bytes) { void* p = ws + off; off = (off + bytes + 255) & ~(size_t)255; return p; };
    bf16*  U    = (bf16*) alloc((size_t)ROWS * KT * 2);        // 73.4 MB
    bf16*  BT   = (bf16*) alloc((size_t)512 * KT * 2);         // 18.4 MB
    bf16*  PB   = (bf16*) alloc((size_t)512 * PBLD * 2);       //  3.7 MB
    bf16*  BTT  = (bf16*) alloc((size_t)1024 * 1024 * 2);      //  2.1 MB
    bf16*  Myb  = (bf16*) alloc((size_t)512 * 1024 * 2);       //  1.0 MB
    float* z    = (float*)alloc((size_t)ROWS * D_ * 4);        //  4.2 MB
    bf16*  zb   = (bf16*) alloc((size_t)B_ * ZBROWS * 512 * 2);//  2.1 MB
    // overlapped region: {W + uPT + Wzero} dead after conv8; bf16 partD
    // written after; partD dead after k_ztaps; bf16 partR written after.
    char*  region = (char*)alloc((size_t)16 * ROWS * D_ * 2);  // 32 MB
    bf16*  W    = (bf16*)region;                               //  6.3 MB (768 tiles)
    bf16*  uPT  = (bf16*)(region + (size_t)768 * 4096 * 2);    //  2.1 MB
    // Wzero at W + WZOFF (elements) = region + 8.4 MB, 8 KB
    bf16*  partD = (bf16*)region;                              // 14 x 2 MB
    bf16*  partR = (bf16*)region;                              //  6 x 2 MB

    // all preps (1 launch; last block zeroes the conv8 zero-tile)
    prep_all<<<7873, 256, 0, stream>>>(u, fil, Mu, My, Mp, Mm,
                                       U, BT, PB, W, Myb, BTT, uPT);

    // Stage C: 8-phase 256x256 conv + 8-wave phi (24 phi + 512 conv blocks)
    conv8<<<536, 512, 0, stream>>>(W, uPT, U, PB, BTT, Myb);

    // Stage D: 256x256 tiles, split-K 14, 8-phase + T1 swizzle + doubling1
    gemm_d<<<256, 512, 0, stream>>>(U, BT, partD, PB, BTT);

    // reduce partials -> z + guarded bf16 copy; Phi doubling2 (3-buf, bid<32)
    k_ztaps<<<1057, 256, 0, stream>>>(partD, z, zb, PB, BTT);

    // Stage R: tap-partials, A = z taps in-place (6 splits = 1 tap each)
    gemm_r<<<dim3(16, 4, SPLITR), 256, 0, stream>>>(zb, PB + 512, partR);

    // out = z + sum partR
    reduce_out<<<(ROWS * D_ / 4 + 255) / 256, 256, 0, stream>>>(z, partR, out);
}